// Round 13
// baseline (10688.038 us; speedup 1.0000x reference)
//
#include <hip/hip_runtime.h>
#include <math.h>

#define BB 16
#define DTOT 544
#define TT_DIM 4096
#define DS 512
#define NCODES 4096
#define HALFV 7.5f
#define EPSV 1e-5f
#define NROWS (BB * TT_DIM)          // 65536
#define NT 16                        // 4096 / 256
#define MT 256                       // 65536 / 256
#define REFINE_THR 0.05f
#define TT 32                        // t per block in k_sem

typedef short bf16x8 __attribute__((ext_vector_type(8)));
typedef float f32x4 __attribute__((ext_vector_type(4)));

__device__ __forceinline__ unsigned short f2bf(float v) {
    unsigned u = __float_as_uint(v);
    unsigned r = (u + 0x7fffu + ((u >> 16) & 1u)) >> 16;
    return (unsigned short)r;
}
__device__ __forceinline__ float bf2f(unsigned short h) {
    return __uint_as_float((unsigned)h << 16);
}

// ---------------- kernel: emb fp32 + e2 + zero flag counter ----------------
__global__ __launch_bounds__(256) void k_emb(const float* __restrict__ esum,
                                             const float* __restrict__ usage,
                                             float* __restrict__ emb,
                                             float* __restrict__ e2,
                                             int* __restrict__ counter) {
    int c = blockIdx.x;
    if (c == 0 && threadIdx.x == 0) *counter = 0;
    float u = usage[c];
    u = (u < EPSV) ? EPSV : u;
    float s = 0.f;
#pragma unroll
    for (int i = 0; i < 2; i++) {
        int d = threadIdx.x + i * 256;
        float v = esum[(size_t)c * DS + d] / u;
        emb[(size_t)c * DS + d] = v;
        s += v * v;
    }
#pragma unroll
    for (int o = 32; o; o >>= 1) s += __shfl_down(s, o, 64);
    __shared__ float red[4];
    if ((threadIdx.x & 63) == 0) red[threadIdx.x >> 6] = s;
    __syncthreads();
    if (threadIdx.x == 0) e2[c] = red[0] + red[1] + red[2] + red[3];
}

// ---------------- pack A: x sem -> 256row x 32K bf16 tiles (chunks: 16 hi, 16 lo) ----------------
// tile byte layout (matches LDS image): off = row*64 + ((u ^ ((row>>1)&3))<<4) + (k&7)*2, u = k>>3
__global__ __launch_bounds__(256) void k_packA(const float* __restrict__ x,
                                               char* __restrict__ Ap) {
    __shared__ char ldsH[16384];
    __shared__ char ldsL[16384];
    int mt = blockIdx.x, dc = blockIdx.y;
    int b = mt >> 4;
    int t0 = (mt & 15) * 256;
    int tid = threadIdx.x;
#pragma unroll
    for (int i = 0; i < 8; i++) {
        int idx = tid + i * 256;
        int d = idx >> 6;            // 0..31
        int t4 = idx & 63;           // 0..63
        float4 v = *(const float4*)&x[((size_t)b * DTOT + dc * 32 + d) * TT_DIM + t0 + t4 * 4];
        float va[4] = {v.x, v.y, v.z, v.w};
        int u = d >> 3;
        int kb = (d & 7) * 2;
#pragma unroll
        for (int j = 0; j < 4; j++) {
            int row = t4 * 4 + j;
            unsigned short hi = f2bf(va[j]);
            unsigned short lo = f2bf(va[j] - bf2f(hi));
            int off = row * 64 + ((u ^ ((row >> 1) & 3)) << 4) + kb;
            *(unsigned short*)&ldsH[off] = hi;
            *(unsigned short*)&ldsL[off] = lo;
        }
    }
    __syncthreads();
    char* gH = Ap + ((size_t)mt * 32 + dc) * 16384;
    char* gL = Ap + ((size_t)mt * 32 + 16 + dc) * 16384;
#pragma unroll
    for (int i = 0; i < 4; i++) {
        int off = (tid + i * 256) * 16;
        *(uint4*)&gH[off] = *(const uint4*)&ldsH[off];
        *(uint4*)&gL[off] = *(const uint4*)&ldsL[off];
    }
}

// ---------------- pack B: emb -> 256code x 32K bf16 tiles (chunks: 16 hi, 16 lo) ----------------
__global__ __launch_bounds__(256) void k_packB(const float* __restrict__ emb,
                                               char* __restrict__ Bp) {
    __shared__ char ldsT[16384];
    int nt = blockIdx.x, c = blockIdx.y;
    int lo_flag = (c >= 16);
    int d0 = (lo_flag ? (c - 16) : c) * 32;
    int c0 = nt * 256;
    int tid = threadIdx.x;
#pragma unroll
    for (int i = 0; i < 8; i++) {
        int idx = tid + i * 256;
        int row = idx >> 3;          // code 0..255
        int f4 = idx & 7;            // d-float4 0..7
        float4 v = *(const float4*)&emb[(size_t)(c0 + row) * DS + d0 + f4 * 4];
        float va[4] = {v.x, v.y, v.z, v.w};
        unsigned short wv[4];
#pragma unroll
        for (int j = 0; j < 4; j++) {
            unsigned short hi = f2bf(va[j]);
            wv[j] = lo_flag ? f2bf(va[j] - bf2f(hi)) : hi;
        }
        int u = f4 >> 1;
        int off = row * 64 + ((u ^ ((row >> 1) & 3)) << 4) + (f4 & 1) * 8;
        uint2 pk;
        pk.x = ((unsigned)wv[1] << 16) | wv[0];
        pk.y = ((unsigned)wv[3] << 16) | wv[2];
        *(uint2*)&ldsT[off] = pk;
    }
    __syncthreads();
    char* g = Bp + ((size_t)nt * 32 + c) * 16384;
#pragma unroll
    for (int i = 0; i < 4; i++) {
        int off = (tid + i * 256) * 16;
        *(uint4*)&g[off] = *(const uint4*)&ldsT[off];
    }
}

// ---------------- MFMA distance-argmin: 256x256 tile, 16 waves x 64x64, 2-slot dbuf ----------------
// 1024 threads = 16 waves (4M x 4N), wave tile 64x64, acc 64 VGPR.
// __launch_bounds__(1024, 8): 8 waves/SIMD -> 2 blocks/CU (LDS 64 KB each, 128 KB total).
// Cross-block overlap (m114) hides each block's VMW0+barrier under the other's MFMA.
// Per chunk: {read frags slot s&1 | stage s+1 -> slot s^1} -> MFMA -> VMW0 -> BAR.
// WAR: slot s^1's last reads were chunk s-1, complete before s-1's end barrier, which
// precedes this stage. RAW: VMW0 drains the 2 staged loads before the barrier.
#define MM(A, B, C) __builtin_amdgcn_mfma_f32_16x16x32_bf16((A), (B), (C), 0, 0, 0)

#define GLDS(SRC, DOFF)                                                              \
    __builtin_amdgcn_global_load_lds(                                                \
        (const __attribute__((address_space(1))) void*)(SRC),                        \
        (__attribute__((address_space(3))) void*)&lds[DOFF], 16, 0, 0)

#define BAR __builtin_amdgcn_s_barrier()
#define VMW0 asm volatile("s_waitcnt vmcnt(0)" ::: "memory")
#define VMNONE (void)0

// stage 32-K chunk C into slot (C&1): A 16KB + B 16KB, 1 gload each (1024 thr x 16B)
#define STAGE(C) do {                                                                \
    int c_ = (C);                                                                    \
    int at_ = (c_ < 32) ? (c_ & 15) : (c_ - 16);                                     \
    int bt_ = (c_ < 32) ? c_ : (c_ - 32);                                            \
    int sb_ = (c_ & 1) * 32768;                                                      \
    GLDS(Ap_mt + at_ * 16384 + t16, sb_ + t16);                                      \
    GLDS(Bp_nt + bt_ * 16384 + t16, sb_ + 16384 + t16);                              \
} while (0)

// one chunk: read frags of slot S (B then A), stage next, MFMA 4x4, vmcnt, barrier
#define CHUNK(S, DO_STG, VMEND, DO_BAR) do {                                         \
    int sb_ = ((S) & 1) * 32768;                                                     \
    bf16x8 bfv[4], af[4];                                                            \
    _Pragma("unroll")                                                                \
    for (int n_ = 0; n_ < 4; n_++)                                                   \
        bfv[n_] = *(const bf16x8*)&lds[sb_ + offB[n_]];                              \
    _Pragma("unroll")                                                                \
    for (int m_ = 0; m_ < 4; m_++)                                                   \
        af[m_] = *(const bf16x8*)&lds[sb_ + offA[m_]];                               \
    if (DO_STG) STAGE((S) + 1);                                                      \
    __builtin_amdgcn_s_setprio(1);                                                   \
    _Pragma("unroll")                                                                \
    for (int m_ = 0; m_ < 4; m_++)                                                   \
        _Pragma("unroll")                                                            \
        for (int n_ = 0; n_ < 4; n_++)                                               \
            acc[m_][n_] = MM(af[m_], bfv[n_], acc[m_][n_]);                          \
    __builtin_amdgcn_s_setprio(0);                                                   \
    VMEND;                                                                           \
    if (DO_BAR) BAR;                                                                 \
} while (0)

__global__ __launch_bounds__(1024, 8) void k_mfma(const char* __restrict__ Ap,
                                                  const char* __restrict__ Bp,
                                                  const float* __restrict__ e2,
                                                  float* __restrict__ pb,
                                                  int* __restrict__ pi,
                                                  float* __restrict__ ps) {
    extern __shared__ char lds[];
    // XCD-bijective swizzle: 4096 blocks, 8 XCDs -> 512 consecutive lin per XCD
    int bid = blockIdx.x;
    int lin = (bid >> 3) + (bid & 7) * 512;
    int nt = lin & 15;
    int mt = lin >> 4;

    int tid = threadIdx.x;
    int lane = tid & 63;
    int w = tid >> 6;            // 0..15
    int wr = w >> 2, wc = w & 3; // 4M x 4N waves, each 64x64
    int l15 = lane & 15, lhi = lane >> 4;
    int t16 = tid * 16;          // 1024 threads x 16B = 16 KB

    const char* Ap_mt = Ap + (size_t)mt * 32 * 16384;
    const char* Bp_nt = Bp + (size_t)nt * 32 * 16384;

    // fragment byte offsets within a 16KB chunk: row r, granule u=lhi,
    // off = r*64 + ((u ^ ((r>>1)&3))<<4)
    int offA[4], offB[4];
#pragma unroll
    for (int m = 0; m < 4; m++) {
        int r = wr * 64 + m * 16 + l15;
        offA[m] = r * 64 + ((lhi ^ ((r >> 1) & 3)) << 4);
    }
#pragma unroll
    for (int n = 0; n < 4; n++) {
        int r = wc * 64 + n * 16 + l15;
        offB[n] = 16384 + r * 64 + ((lhi ^ ((r >> 1) & 3)) << 4);
    }

    f32x4 acc[4][4];
#pragma unroll
    for (int m = 0; m < 4; m++)
#pragma unroll
        for (int n = 0; n < 4; n++) acc[m][n] = (f32x4){0.f, 0.f, 0.f, 0.f};

    // prologue: stage chunk 0 -> slot 0; drain; barrier
    STAGE(0);
    VMW0;
    BAR;

#pragma unroll 1
    for (int s = 0; s < 47; s++) {
        CHUNK(s, 1, VMW0, 1);
    }
    CHUNK(47, 0, VMNONE, 0);

    // ---------------- epilogue: per-row argmin ----------------
    __syncthreads();
    float* rb = (float*)lds;
    float* rs = (float*)(lds + 4096);
    int*   ri = (int*)(lds + 8192);

    float e2v[4];
#pragma unroll
    for (int n = 0; n < 4; n++)
        e2v[n] = e2[nt * 256 + wc * 64 + n * 16 + l15];

#pragma unroll
    for (int m = 0; m < 4; m++) {
#pragma unroll
        for (int r2 = 0; r2 < 4; r2++) {
            float bst = 3.4e38f, sec = 3.4e38f;
            int bi = 1 << 30;
#pragma unroll
            for (int n = 0; n < 4; n++) {
                float v = e2v[n] - 2.f * acc[m][n][r2];
                int vi = wc * 64 + n * 16 + l15;
                if (v < bst || (v == bst && vi < bi)) { sec = bst; bst = v; bi = vi; }
                else sec = fminf(sec, v);
            }
#pragma unroll
            for (int mask = 1; mask <= 8; mask <<= 1) {
                float ob = __shfl_xor(bst, mask);
                int obi = __shfl_xor(bi, mask);
                float os = __shfl_xor(sec, mask);
                if (ob < bst || (ob == bst && obi < bi)) {
                    sec = fminf(bst, os); bst = ob; bi = obi;
                } else {
                    sec = fminf(sec, ob);
                }
            }
            if (l15 == 0) {
                int rl = wr * 64 + m * 16 + lhi * 4 + r2;
                int slot = wc * 256 + rl;
                rb[slot] = bst; rs[slot] = sec; ri[slot] = nt * 256 + bi;
            }
        }
    }
    __syncthreads();
    if (tid < 256) {
        float bsv = rb[tid], ssv = rs[tid];
        int biv = ri[tid];
#pragma unroll
        for (int c = 1; c < 4; c++) {
            float ob = rb[c * 256 + tid];
            float os = rs[c * 256 + tid];
            int oi = ri[c * 256 + tid];
            if (ob < bsv || (ob == bsv && oi < biv)) { ssv = fminf(bsv, os); bsv = ob; biv = oi; }
            else ssv = fminf(ssv, ob);
        }
        size_t gr = (size_t)mt * 256 + tid;
        pb[(size_t)nt * NROWS + gr] = bsv;
        pi[(size_t)nt * NROWS + gr] = biv;
        ps[(size_t)nt * NROWS + gr] = ssv;
    }
}

// ---------------- reduce partials -> codes + flagged rows ----------------
__global__ __launch_bounds__(256) void k_reduce(const float* __restrict__ pb,
                                                const int* __restrict__ pi,
                                                const float* __restrict__ ps,
                                                int* __restrict__ codes,
                                                int* __restrict__ list,
                                                int* __restrict__ counter) {
    int row = blockIdx.x * 256 + threadIdx.x;
    float b = 3.4e38f, s = 3.4e38f;
    int bi = 1 << 30;
    for (int nt = 0; nt < NT; nt++) {
        float b2 = pb[(size_t)nt * NROWS + row];
        int i2 = pi[(size_t)nt * NROWS + row];
        float s2 = ps[(size_t)nt * NROWS + row];
        if (b2 < b || (b2 == b && i2 < bi)) { s = fminf(b, s2); b = b2; bi = i2; }
        else s = fminf(s, b2);
    }
    codes[row] = bi;
    if (s - b < REFINE_THR) {
        int p = atomicAdd(counter, 1);
        list[p] = row;
    }
}

// ---------------- fp64 full-scan refine of flagged rows ----------------
__global__ __launch_bounds__(256) void k_refine(const float* __restrict__ x,
                                                const float* __restrict__ emb,
                                                int* __restrict__ codes,
                                                const int* __restrict__ list,
                                                const int* __restrict__ counter) {
    __shared__ float xrow[DS];
    __shared__ double redv[256];
    __shared__ int redi[256];
    int tid = threadIdx.x;
    int nflag = *counter;
    for (int it = blockIdx.x; it < nflag; it += gridDim.x) {
        int row = list[it];
        int b = row >> 12;
        int t = row & 4095;
        for (int d = tid; d < DS; d += 256)
            xrow[d] = x[((size_t)b * DTOT + d) * TT_DIM + t];
        __syncthreads();
        double bv = 1e300;
        int bi = 1 << 30;
        for (int c = tid; c < NCODES; c += 256) {
            const float* er = emb + (size_t)c * DS;
            double s = 0.0;
            for (int d = 0; d < DS; d += 4) {
                float4 ev = *(const float4*)&er[d];
                float4 xv = *(const float4*)&xrow[d];
                double d0 = (double)xv.x - (double)ev.x;
                double d1 = (double)xv.y - (double)ev.y;
                double d2 = (double)xv.z - (double)ev.z;
                double d3 = (double)xv.w - (double)ev.w;
                s += d0 * d0 + d1 * d1 + d2 * d2 + d3 * d3;
            }
            if (s < bv || (s == bv && c < bi)) { bv = s; bi = c; }
        }
        redv[tid] = bv; redi[tid] = bi;
        __syncthreads();
        for (int off = 128; off; off >>= 1) {
            if (tid < off) {
                if (redv[tid + off] < redv[tid] ||
                    (redv[tid + off] == redv[tid] && redi[tid + off] < redi[tid])) {
                    redv[tid] = redv[tid + off];
                    redi[tid] = redi[tid + off];
                }
            }
            __syncthreads();
        }
        if (tid == 0) codes[row] = redi[0];
        __syncthreads();
    }
}

// ---------------- sem output (gather or copy) + sem codes ----------------
__global__ __launch_bounds__(256) void k_sem(const float* __restrict__ x,
                                             const float* __restrict__ emb,
                                             const int* __restrict__ codes,
                                             const float* __restrict__ sem_probs,
                                             float* __restrict__ out) {
    __shared__ float q[TT * (DS + 1)];
    __shared__ int rowc[TT];
    int b = blockIdx.y, t0 = blockIdx.x * TT;
    bool mask = sem_probs[b] < 0.5f;
    float* outb = out + (size_t)b * DTOT * TT_DIM + t0;
    const float* xb = x + (size_t)b * DTOT * TT_DIM + t0;
    const size_t QOFF = (size_t)BB * DTOT * TT_DIM;

    if (threadIdx.x < TT) {
        int code = codes[b * TT_DIM + t0 + threadIdx.x];
        rowc[threadIdx.x] = code;
        out[QOFF + ((size_t)b * 33) * TT_DIM + t0 + threadIdx.x] = (float)code;
    }
    __syncthreads();

    if (mask) {
        for (int i = 0; i < TT * DS / 256; i++) {
            int idx = threadIdx.x + i * 256;
            int tt = idx >> 9, d = idx & 511;
            q[tt * (DS + 1) + d] = emb[(size_t)rowc[tt] * DS + d];
        }
        __syncthreads();
        for (int i = 0; i < TT * DS / 256; i++) {
            int idx = threadIdx.x + i * 256;
            int d = idx >> 5, tt = idx & 31;
            outb[(size_t)d * TT_DIM + tt] = q[tt * (DS + 1) + d];
        }
    } else {
        for (int i = 0; i < TT * DS / 256; i++) {
            int idx = threadIdx.x + i * 256;
            int d = idx >> 5, tt = idx & 31;
            outb[(size_t)d * TT_DIM + tt] = xb[(size_t)d * TT_DIM + tt];
        }
    }
}

// ---------------- aco elementwise ----------------
__global__ __launch_bounds__(256) void k_aco(const float* __restrict__ x,
                                             const float* __restrict__ noise,
                                             const float* __restrict__ aco_probs,
                                             float* __restrict__ out) {
    int idx = blockIdx.x * 256 + threadIdx.x;
    int t4 = idx & 1023;
    int bc = idx >> 10;
    int ch = bc & 31;
    int b = bc >> 5;
    const float4 xv = *(const float4*)&x[((size_t)(b * DTOT + DS + ch)) * TT_DIM + t4 * 4];
    const float4 nv = *(const float4*)&noise[((size_t)(b * 32 + ch)) * TT_DIM + t4 * 4];
    float p = aco_probs[b];
    const size_t QOFF = (size_t)BB * DTOT * TT_DIM;

    float zq[4], cq[4];
    float xa[4] = {xv.x, xv.y, xv.z, xv.w};
    float na[4] = {nv.x, nv.y, nv.z, nv.w};
#pragma unroll
    for (int i = 0; i < 4; i++) {
        float zb = tanhf(xa[i]) * HALFV;
        float z;
        if (p < 0.5f) z = rintf(zb);
        else if (p < 0.75f) z = fminf(fmaxf(zb + na[i], -HALFV), HALFV);
        else z = zb;
        zq[i] = z / HALFV;
        cq[i] = fminf(fmaxf(rintf(z + HALFV), 0.f), 15.f);
    }
    float4 qo = {zq[0], zq[1], zq[2], zq[3]};
    float4 co = {cq[0], cq[1], cq[2], cq[3]};
    *(float4*)&out[((size_t)(b * DTOT + DS + ch)) * TT_DIM + t4 * 4] = qo;
    *(float4*)&out[QOFF + ((size_t)(b * 33 + 1 + ch)) * TT_DIM + t4 * 4] = co;
}

extern "C" void kernel_launch(void* const* d_in, const int* in_sizes, int n_in,
                              void* d_out, int out_size, void* d_ws, size_t ws_size,
                              hipStream_t stream) {
    const float* x         = (const float*)d_in[0];
    const float* esum      = (const float*)d_in[1];
    const float* usage     = (const float*)d_in[2];
    const float* sem_probs = (const float*)d_in[3];
    const float* aco_probs = (const float*)d_in[4];
    const float* noise     = (const float*)d_in[5];
    float* out = (float*)d_out;

    char* w = (char*)d_ws;
    float* emb    = (float*)w;                         // 8,388,608
    float* e2     = (float*)(w + 8388608);             // 16,384
    char*  Ap     = w + 8404992;                       // 134,217,728
    char*  Bp     = w + 142622720;                     // 8,388,608
    float* pb     = (float*)(w + 151011328);           // 4,194,304
    int*   pi     = (int*)(w + 155205632);             // 4,194,304
    float* ps     = (float*)(w + 159399936);           // 4,194,304
    int*   codes  = (int*)(w + 163594240);             // 262,144
    int*   list   = (int*)(w + 163856384);             // 262,144
    int*   counter= (int*)(w + 164118528);             // 4

    k_emb<<<NCODES, 256, 0, stream>>>(esum, usage, emb, e2, counter);
    k_packA<<<dim3(MT, 16), 256, 0, stream>>>(x, Ap);
    k_packB<<<dim3(NT, 32), 256, 0, stream>>>(emb, Bp);
    k_mfma<<<NT * MT, 1024, 65536, stream>>>(Ap, Bp, e2, pb, pi, ps);
    k_reduce<<<NROWS / 256, 256, 0, stream>>>(pb, pi, ps, codes, list, counter);
    k_refine<<<256, 256, 0, stream>>>(x, emb, codes, list, counter);
    k_sem<<<dim3(TT_DIM / TT, BB), 256, 0, stream>>>(x, emb, codes, sem_probs, out);
    k_aco<<<(BB * 32 * TT_DIM) / (256 * 4), 256, 0, stream>>>(x, noise, aco_probs, out);
}

// Round 14
// 1188.550 us; speedup vs baseline: 8.9925x; 8.9925x over previous
//
#include <hip/hip_runtime.h>
#include <math.h>

#define BB 16
#define DTOT 544
#define TT_DIM 4096
#define DS 512
#define NCODES 4096
#define HALFV 7.5f
#define EPSV 1e-5f
#define NROWS (BB * TT_DIM)          // 65536
#define NT 16                        // 4096 / 256
#define MT 256                       // 65536 / 256
#define REFINE_THR 0.05f
#define TT 32                        // t per block in k_sem

typedef short bf16x8 __attribute__((ext_vector_type(8)));
typedef float f32x4 __attribute__((ext_vector_type(4)));

__device__ __forceinline__ unsigned short f2bf(float v) {
    unsigned u = __float_as_uint(v);
    unsigned r = (u + 0x7fffu + ((u >> 16) & 1u)) >> 16;
    return (unsigned short)r;
}
__device__ __forceinline__ float bf2f(unsigned short h) {
    return __uint_as_float((unsigned)h << 16);
}

// ---------------- kernel: emb fp32 + e2 + zero flag counter ----------------
__global__ __launch_bounds__(256) void k_emb(const float* __restrict__ esum,
                                             const float* __restrict__ usage,
                                             float* __restrict__ emb,
                                             float* __restrict__ e2,
                                             int* __restrict__ counter) {
    int c = blockIdx.x;
    if (c == 0 && threadIdx.x == 0) *counter = 0;
    float u = usage[c];
    u = (u < EPSV) ? EPSV : u;
    float s = 0.f;
#pragma unroll
    for (int i = 0; i < 2; i++) {
        int d = threadIdx.x + i * 256;
        float v = esum[(size_t)c * DS + d] / u;
        emb[(size_t)c * DS + d] = v;
        s += v * v;
    }
#pragma unroll
    for (int o = 32; o; o >>= 1) s += __shfl_down(s, o, 64);
    __shared__ float red[4];
    if ((threadIdx.x & 63) == 0) red[threadIdx.x >> 6] = s;
    __syncthreads();
    if (threadIdx.x == 0) e2[c] = red[0] + red[1] + red[2] + red[3];
}

// ---------------- pack A: x sem -> 256row x 32K bf16 tiles (chunks: 16 hi, 16 lo) ----------------
// tile byte layout (matches LDS image): off = row*64 + ((u ^ ((row>>1)&3))<<4) + (k&7)*2, u = k>>3
__global__ __launch_bounds__(256) void k_packA(const float* __restrict__ x,
                                               char* __restrict__ Ap) {
    __shared__ char ldsH[16384];
    __shared__ char ldsL[16384];
    int mt = blockIdx.x, dc = blockIdx.y;
    int b = mt >> 4;
    int t0 = (mt & 15) * 256;
    int tid = threadIdx.x;
#pragma unroll
    for (int i = 0; i < 8; i++) {
        int idx = tid + i * 256;
        int d = idx >> 6;            // 0..31
        int t4 = idx & 63;           // 0..63
        float4 v = *(const float4*)&x[((size_t)b * DTOT + dc * 32 + d) * TT_DIM + t0 + t4 * 4];
        float va[4] = {v.x, v.y, v.z, v.w};
        int u = d >> 3;
        int kb = (d & 7) * 2;
#pragma unroll
        for (int j = 0; j < 4; j++) {
            int row = t4 * 4 + j;
            unsigned short hi = f2bf(va[j]);
            unsigned short lo = f2bf(va[j] - bf2f(hi));
            int off = row * 64 + ((u ^ ((row >> 1) & 3)) << 4) + kb;
            *(unsigned short*)&ldsH[off] = hi;
            *(unsigned short*)&ldsL[off] = lo;
        }
    }
    __syncthreads();
    char* gH = Ap + ((size_t)mt * 32 + dc) * 16384;
    char* gL = Ap + ((size_t)mt * 32 + 16 + dc) * 16384;
#pragma unroll
    for (int i = 0; i < 4; i++) {
        int off = (tid + i * 256) * 16;
        *(uint4*)&gH[off] = *(const uint4*)&ldsH[off];
        *(uint4*)&gL[off] = *(const uint4*)&ldsL[off];
    }
}

// ---------------- pack B: emb -> 256code x 32K bf16 tiles (chunks: 16 hi, 16 lo) ----------------
__global__ __launch_bounds__(256) void k_packB(const float* __restrict__ emb,
                                               char* __restrict__ Bp) {
    __shared__ char ldsT[16384];
    int nt = blockIdx.x, c = blockIdx.y;
    int lo_flag = (c >= 16);
    int d0 = (lo_flag ? (c - 16) : c) * 32;
    int c0 = nt * 256;
    int tid = threadIdx.x;
#pragma unroll
    for (int i = 0; i < 8; i++) {
        int idx = tid + i * 256;
        int row = idx >> 3;          // code 0..255
        int f4 = idx & 7;            // d-float4 0..7
        float4 v = *(const float4*)&emb[(size_t)(c0 + row) * DS + d0 + f4 * 4];
        float va[4] = {v.x, v.y, v.z, v.w};
        unsigned short wv[4];
#pragma unroll
        for (int j = 0; j < 4; j++) {
            unsigned short hi = f2bf(va[j]);
            wv[j] = lo_flag ? f2bf(va[j] - bf2f(hi)) : hi;
        }
        int u = f4 >> 1;
        int off = row * 64 + ((u ^ ((row >> 1) & 3)) << 4) + (f4 & 1) * 8;
        uint2 pk;
        pk.x = ((unsigned)wv[1] << 16) | wv[0];
        pk.y = ((unsigned)wv[3] << 16) | wv[2];
        *(uint2*)&ldsT[off] = pk;
    }
    __syncthreads();
    char* g = Bp + ((size_t)nt * 32 + c) * 16384;
#pragma unroll
    for (int i = 0; i < 4; i++) {
        int off = (tid + i * 256) * 16;
        *(uint4*)&g[off] = *(const uint4*)&ldsT[off];
    }
}

// ---------------- MFMA distance-argmin: 256x256 tile, 16 waves x 64x64, BK=64 2-slot dbuf ----------------
// Round-12 geometry (proven 873us, MfmaUtil 44.5, VGPR 64, 4 waves/SIMD) with ONE delta:
// two 32-K chunks per sync step. Slot T&1 = [A h0 16K][A h1 16K][B h0 16K][B h1 16K] = 64KB,
// 2 slots = 128KB, 1 block/CU. Per step: read h0 frags | stage step T+1 (4 gloads) ->
// MFMA16 -> read h1 frags -> MFMA16 -> VMW0 -> BAR. 24 barriers (was 48).
// WAR: slot (T+1)&1's last reads were step T-1, complete before T-1's closing barrier.
// RAW: VMW0 drains this step's 4 staged loads before the barrier.
#define MM(A, B, C) __builtin_amdgcn_mfma_f32_16x16x32_bf16((A), (B), (C), 0, 0, 0)

#define GLDS(SRC, DOFF)                                                              \
    __builtin_amdgcn_global_load_lds(                                                \
        (const __attribute__((address_space(1))) void*)(SRC),                        \
        (__attribute__((address_space(3))) void*)&lds[DOFF], 16, 0, 0)

#define BAR __builtin_amdgcn_s_barrier()
#define VMW0 asm volatile("s_waitcnt vmcnt(0)" ::: "memory")
#define VMNONE (void)0

// stage 64-K step T (chunks 2T, 2T+1) into slot (T&1)
#define STAGE64(T) do {                                                              \
    int sb_ = ((T) & 1) * 65536;                                                     \
    _Pragma("unroll")                                                                \
    for (int h_ = 0; h_ < 2; h_++) {                                                 \
        int c_ = 2 * (T) + h_;                                                       \
        int at_ = (c_ < 32) ? (c_ & 15) : (c_ - 16);                                 \
        int bt_ = (c_ < 32) ? c_ : (c_ - 32);                                        \
        GLDS(Ap_mt + at_ * 16384 + t16, sb_ + h_ * 16384 + t16);                     \
        GLDS(Bp_nt + bt_ * 16384 + t16, sb_ + 32768 + h_ * 16384 + t16);             \
    }                                                                                \
} while (0)

// one 64-K step
#define STEP64(T, DO_STG, VMEND, DO_BAR) do {                                        \
    int sb_ = ((T) & 1) * 65536;                                                     \
    bf16x8 bfv[4], af[4];                                                            \
    _Pragma("unroll")                                                                \
    for (int n_ = 0; n_ < 4; n_++)                                                   \
        bfv[n_] = *(const bf16x8*)&lds[sb_ + 32768 + offB[n_]];                      \
    _Pragma("unroll")                                                                \
    for (int m_ = 0; m_ < 4; m_++)                                                   \
        af[m_] = *(const bf16x8*)&lds[sb_ + offA[m_]];                               \
    if (DO_STG) STAGE64((T) + 1);                                                    \
    __builtin_amdgcn_s_setprio(1);                                                   \
    _Pragma("unroll")                                                                \
    for (int m_ = 0; m_ < 4; m_++)                                                   \
        _Pragma("unroll")                                                            \
        for (int n_ = 0; n_ < 4; n_++)                                               \
            acc[m_][n_] = MM(af[m_], bfv[n_], acc[m_][n_]);                          \
    __builtin_amdgcn_s_setprio(0);                                                   \
    _Pragma("unroll")                                                                \
    for (int n_ = 0; n_ < 4; n_++)                                                   \
        bfv[n_] = *(const bf16x8*)&lds[sb_ + 49152 + offB[n_]];                      \
    _Pragma("unroll")                                                                \
    for (int m_ = 0; m_ < 4; m_++)                                                   \
        af[m_] = *(const bf16x8*)&lds[sb_ + 16384 + offA[m_]];                       \
    __builtin_amdgcn_s_setprio(1);                                                   \
    _Pragma("unroll")                                                                \
    for (int m_ = 0; m_ < 4; m_++)                                                   \
        _Pragma("unroll")                                                            \
        for (int n_ = 0; n_ < 4; n_++)                                               \
            acc[m_][n_] = MM(af[m_], bfv[n_], acc[m_][n_]);                          \
    __builtin_amdgcn_s_setprio(0);                                                   \
    VMEND;                                                                           \
    if (DO_BAR) BAR;                                                                 \
} while (0)

__global__ __launch_bounds__(1024, 4) void k_mfma(const char* __restrict__ Ap,
                                                  const char* __restrict__ Bp,
                                                  const float* __restrict__ e2,
                                                  float* __restrict__ pb,
                                                  int* __restrict__ pi,
                                                  float* __restrict__ ps) {
    extern __shared__ char lds[];
    // XCD-bijective swizzle: 4096 blocks, 8 XCDs -> 512 consecutive lin per XCD
    int bid = blockIdx.x;
    int lin = (bid >> 3) + (bid & 7) * 512;
    int nt = lin & 15;
    int mt = lin >> 4;

    int tid = threadIdx.x;
    int lane = tid & 63;
    int w = tid >> 6;            // 0..15
    int wr = w >> 2, wc = w & 3; // 4M x 4N waves, each 64x64
    int l15 = lane & 15, lhi = lane >> 4;
    int t16 = tid * 16;          // 1024 threads x 16B = 16 KB

    const char* Ap_mt = Ap + (size_t)mt * 32 * 16384;
    const char* Bp_nt = Bp + (size_t)nt * 32 * 16384;

    // fragment byte offsets within a 16KB chunk image: row r, granule u=lhi,
    // off = r*64 + ((u ^ ((r>>1)&3))<<4)
    int offA[4], offB[4];
#pragma unroll
    for (int m = 0; m < 4; m++) {
        int r = wr * 64 + m * 16 + l15;
        offA[m] = r * 64 + ((lhi ^ ((r >> 1) & 3)) << 4);
    }
#pragma unroll
    for (int n = 0; n < 4; n++) {
        int r = wc * 64 + n * 16 + l15;
        offB[n] = r * 64 + ((lhi ^ ((r >> 1) & 3)) << 4);
    }

    f32x4 acc[4][4];
#pragma unroll
    for (int m = 0; m < 4; m++)
#pragma unroll
        for (int n = 0; n < 4; n++) acc[m][n] = (f32x4){0.f, 0.f, 0.f, 0.f};

    // prologue: stage step 0 (chunks 0,1) -> slot 0; drain; barrier
    STAGE64(0);
    VMW0;
    BAR;

#pragma unroll 1
    for (int t = 0; t < 23; t++) {
        STEP64(t, 1, VMW0, 1);
    }
    STEP64(23, 0, VMNONE, 0);

    // ---------------- epilogue: per-row argmin ----------------
    __syncthreads();
    float* rb = (float*)lds;
    float* rs = (float*)(lds + 4096);
    int*   ri = (int*)(lds + 8192);

    float e2v[4];
#pragma unroll
    for (int n = 0; n < 4; n++)
        e2v[n] = e2[nt * 256 + wc * 64 + n * 16 + l15];

#pragma unroll
    for (int m = 0; m < 4; m++) {
#pragma unroll
        for (int r2 = 0; r2 < 4; r2++) {
            float bst = 3.4e38f, sec = 3.4e38f;
            int bi = 1 << 30;
#pragma unroll
            for (int n = 0; n < 4; n++) {
                float v = e2v[n] - 2.f * acc[m][n][r2];
                int vi = wc * 64 + n * 16 + l15;
                if (v < bst || (v == bst && vi < bi)) { sec = bst; bst = v; bi = vi; }
                else sec = fminf(sec, v);
            }
#pragma unroll
            for (int mask = 1; mask <= 8; mask <<= 1) {
                float ob = __shfl_xor(bst, mask);
                int obi = __shfl_xor(bi, mask);
                float os = __shfl_xor(sec, mask);
                if (ob < bst || (ob == bst && obi < bi)) {
                    sec = fminf(bst, os); bst = ob; bi = obi;
                } else {
                    sec = fminf(sec, ob);
                }
            }
            if (l15 == 0) {
                int rl = wr * 64 + m * 16 + lhi * 4 + r2;
                int slot = wc * 256 + rl;
                rb[slot] = bst; rs[slot] = sec; ri[slot] = nt * 256 + bi;
            }
        }
    }
    __syncthreads();
    if (tid < 256) {
        float bsv = rb[tid], ssv = rs[tid];
        int biv = ri[tid];
#pragma unroll
        for (int c = 1; c < 4; c++) {
            float ob = rb[c * 256 + tid];
            float os = rs[c * 256 + tid];
            int oi = ri[c * 256 + tid];
            if (ob < bsv || (ob == bsv && oi < biv)) { ssv = fminf(bsv, os); bsv = ob; biv = oi; }
            else ssv = fminf(ssv, ob);
        }
        size_t gr = (size_t)mt * 256 + tid;
        pb[(size_t)nt * NROWS + gr] = bsv;
        pi[(size_t)nt * NROWS + gr] = biv;
        ps[(size_t)nt * NROWS + gr] = ssv;
    }
}

// ---------------- reduce partials -> codes + flagged rows ----------------
__global__ __launch_bounds__(256) void k_reduce(const float* __restrict__ pb,
                                                const int* __restrict__ pi,
                                                const float* __restrict__ ps,
                                                int* __restrict__ codes,
                                                int* __restrict__ list,
                                                int* __restrict__ counter) {
    int row = blockIdx.x * 256 + threadIdx.x;
    float b = 3.4e38f, s = 3.4e38f;
    int bi = 1 << 30;
    for (int nt = 0; nt < NT; nt++) {
        float b2 = pb[(size_t)nt * NROWS + row];
        int i2 = pi[(size_t)nt * NROWS + row];
        float s2 = ps[(size_t)nt * NROWS + row];
        if (b2 < b || (b2 == b && i2 < bi)) { s = fminf(b, s2); b = b2; bi = i2; }
        else s = fminf(s, b2);
    }
    codes[row] = bi;
    if (s - b < REFINE_THR) {
        int p = atomicAdd(counter, 1);
        list[p] = row;
    }
}

// ---------------- fp64 full-scan refine of flagged rows ----------------
__global__ __launch_bounds__(256) void k_refine(const float* __restrict__ x,
                                                const float* __restrict__ emb,
                                                int* __restrict__ codes,
                                                const int* __restrict__ list,
                                                const int* __restrict__ counter) {
    __shared__ float xrow[DS];
    __shared__ double redv[256];
    __shared__ int redi[256];
    int tid = threadIdx.x;
    int nflag = *counter;
    for (int it = blockIdx.x; it < nflag; it += gridDim.x) {
        int row = list[it];
        int b = row >> 12;
        int t = row & 4095;
        for (int d = tid; d < DS; d += 256)
            xrow[d] = x[((size_t)b * DTOT + d) * TT_DIM + t];
        __syncthreads();
        double bv = 1e300;
        int bi = 1 << 30;
        for (int c = tid; c < NCODES; c += 256) {
            const float* er = emb + (size_t)c * DS;
            double s = 0.0;
            for (int d = 0; d < DS; d += 4) {
                float4 ev = *(const float4*)&er[d];
                float4 xv = *(const float4*)&xrow[d];
                double d0 = (double)xv.x - (double)ev.x;
                double d1 = (double)xv.y - (double)ev.y;
                double d2 = (double)xv.z - (double)ev.z;
                double d3 = (double)xv.w - (double)ev.w;
                s += d0 * d0 + d1 * d1 + d2 * d2 + d3 * d3;
            }
            if (s < bv || (s == bv && c < bi)) { bv = s; bi = c; }
        }
        redv[tid] = bv; redi[tid] = bi;
        __syncthreads();
        for (int off = 128; off; off >>= 1) {
            if (tid < off) {
                if (redv[tid + off] < redv[tid] ||
                    (redv[tid + off] == redv[tid] && redi[tid + off] < redi[tid])) {
                    redv[tid] = redv[tid + off];
                    redi[tid] = redi[tid + off];
                }
            }
            __syncthreads();
        }
        if (tid == 0) codes[row] = redi[0];
        __syncthreads();
    }
}

// ---------------- sem output (gather or copy) + sem codes ----------------
__global__ __launch_bounds__(256) void k_sem(const float* __restrict__ x,
                                             const float* __restrict__ emb,
                                             const int* __restrict__ codes,
                                             const float* __restrict__ sem_probs,
                                             float* __restrict__ out) {
    __shared__ float q[TT * (DS + 1)];
    __shared__ int rowc[TT];
    int b = blockIdx.y, t0 = blockIdx.x * TT;
    bool mask = sem_probs[b] < 0.5f;
    float* outb = out + (size_t)b * DTOT * TT_DIM + t0;
    const float* xb = x + (size_t)b * DTOT * TT_DIM + t0;
    const size_t QOFF = (size_t)BB * DTOT * TT_DIM;

    if (threadIdx.x < TT) {
        int code = codes[b * TT_DIM + t0 + threadIdx.x];
        rowc[threadIdx.x] = code;
        out[QOFF + ((size_t)b * 33) * TT_DIM + t0 + threadIdx.x] = (float)code;
    }
    __syncthreads();

    if (mask) {
        for (int i = 0; i < TT * DS / 256; i++) {
            int idx = threadIdx.x + i * 256;
            int tt = idx >> 9, d = idx & 511;
            q[tt * (DS + 1) + d] = emb[(size_t)rowc[tt] * DS + d];
        }
        __syncthreads();
        for (int i = 0; i < TT * DS / 256; i++) {
            int idx = threadIdx.x + i * 256;
            int d = idx >> 5, tt = idx & 31;
            outb[(size_t)d * TT_DIM + tt] = q[tt * (DS + 1) + d];
        }
    } else {
        for (int i = 0; i < TT * DS / 256; i++) {
            int idx = threadIdx.x + i * 256;
            int d = idx >> 5, tt = idx & 31;
            outb[(size_t)d * TT_DIM + tt] = xb[(size_t)d * TT_DIM + tt];
        }
    }
}

// ---------------- aco elementwise ----------------
__global__ __launch_bounds__(256) void k_aco(const float* __restrict__ x,
                                             const float* __restrict__ noise,
                                             const float* __restrict__ aco_probs,
                                             float* __restrict__ out) {
    int idx = blockIdx.x * 256 + threadIdx.x;
    int t4 = idx & 1023;
    int bc = idx >> 10;
    int ch = bc & 31;
    int b = bc >> 5;
    const float4 xv = *(const float4*)&x[((size_t)(b * DTOT + DS + ch)) * TT_DIM + t4 * 4];
    const float4 nv = *(const float4*)&noise[((size_t)(b * 32 + ch)) * TT_DIM + t4 * 4];
    float p = aco_probs[b];
    const size_t QOFF = (size_t)BB * DTOT * TT_DIM;

    float zq[4], cq[4];
    float xa[4] = {xv.x, xv.y, xv.z, xv.w};
    float na[4] = {nv.x, nv.y, nv.z, nv.w};
#pragma unroll
    for (int i = 0; i < 4; i++) {
        float zb = tanhf(xa[i]) * HALFV;
        float z;
        if (p < 0.5f) z = rintf(zb);
        else if (p < 0.75f) z = fminf(fmaxf(zb + na[i], -HALFV), HALFV);
        else z = zb;
        zq[i] = z / HALFV;
        cq[i] = fminf(fmaxf(rintf(z + HALFV), 0.f), 15.f);
    }
    float4 qo = {zq[0], zq[1], zq[2], zq[3]};
    float4 co = {cq[0], cq[1], cq[2], cq[3]};
    *(float4*)&out[((size_t)(b * DTOT + DS + ch)) * TT_DIM + t4 * 4] = qo;
    *(float4*)&out[QOFF + ((size_t)(b * 33 + 1 + ch)) * TT_DIM + t4 * 4] = co;
}

extern "C" void kernel_launch(void* const* d_in, const int* in_sizes, int n_in,
                              void* d_out, int out_size, void* d_ws, size_t ws_size,
                              hipStream_t stream) {
    const float* x         = (const float*)d_in[0];
    const float* esum      = (const float*)d_in[1];
    const float* usage     = (const float*)d_in[2];
    const float* sem_probs = (const float*)d_in[3];
    const float* aco_probs = (const float*)d_in[4];
    const float* noise     = (const float*)d_in[5];
    float* out = (float*)d_out;

    char* w = (char*)d_ws;
    float* emb    = (float*)w;                         // 8,388,608
    float* e2     = (float*)(w + 8388608);             // 16,384
    char*  Ap     = w + 8404992;                       // 134,217,728
    char*  Bp     = w + 142622720;                     // 8,388,608
    float* pb     = (float*)(w + 151011328);           // 4,194,304
    int*   pi     = (int*)(w + 155205632);             // 4,194,304
    float* ps     = (float*)(w + 159399936);           // 4,194,304
    int*   codes  = (int*)(w + 163594240);             // 262,144
    int*   list   = (int*)(w + 163856384);             // 262,144
    int*   counter= (int*)(w + 164118528);             // 4

    k_emb<<<NCODES, 256, 0, stream>>>(esum, usage, emb, e2, counter);
    k_packA<<<dim3(MT, 16), 256, 0, stream>>>(x, Ap);
    k_packB<<<dim3(NT, 32), 256, 0, stream>>>(emb, Bp);
    k_mfma<<<NT * MT, 1024, 131072, stream>>>(Ap, Bp, e2, pb, pi, ps);
    k_reduce<<<NROWS / 256, 256, 0, stream>>>(pb, pi, ps, codes, list, counter);
    k_refine<<<256, 256, 0, stream>>>(x, emb, codes, list, counter);
    k_sem<<<dim3(TT_DIM / TT, BB), 256, 0, stream>>>(x, emb, codes, sem_probs, out);
    k_aco<<<(BB * 32 * TT_DIM) / (256 * 4), 256, 0, stream>>>(x, noise, aco_probs, out);
}

// Round 15
// 1171.290 us; speedup vs baseline: 9.1250x; 1.0147x over previous
//
#include <hip/hip_runtime.h>
#include <math.h>

#define BB 16
#define DTOT 544
#define TT_DIM 4096
#define DS 512
#define NCODES 4096
#define HALFV 7.5f
#define EPSV 1e-5f
#define NROWS (BB * TT_DIM)          // 65536
#define NT 16                        // 4096 / 256
#define MT 256                       // 65536 / 256
#define REFINE_THR 0.02f
#define TT 32                        // t per block in k_sem

typedef short bf16x8 __attribute__((ext_vector_type(8)));
typedef float f32x4 __attribute__((ext_vector_type(4)));

__device__ __forceinline__ unsigned short f2bf(float v) {
    unsigned u = __float_as_uint(v);
    unsigned r = (u + 0x7fffu + ((u >> 16) & 1u)) >> 16;
    return (unsigned short)r;
}
__device__ __forceinline__ float bf2f(unsigned short h) {
    return __uint_as_float((unsigned)h << 16);
}

// ---------------- kernel: emb fp32 + e2 + zero flag counter ----------------
__global__ __launch_bounds__(256) void k_emb(const float* __restrict__ esum,
                                             const float* __restrict__ usage,
                                             float* __restrict__ emb,
                                             float* __restrict__ e2,
                                             int* __restrict__ counter) {
    int c = blockIdx.x;
    if (c == 0 && threadIdx.x == 0) *counter = 0;
    float u = usage[c];
    u = (u < EPSV) ? EPSV : u;
    float s = 0.f;
#pragma unroll
    for (int i = 0; i < 2; i++) {
        int d = threadIdx.x + i * 256;
        float v = esum[(size_t)c * DS + d] / u;
        emb[(size_t)c * DS + d] = v;
        s += v * v;
    }
#pragma unroll
    for (int o = 32; o; o >>= 1) s += __shfl_down(s, o, 64);
    __shared__ float red[4];
    if ((threadIdx.x & 63) == 0) red[threadIdx.x >> 6] = s;
    __syncthreads();
    if (threadIdx.x == 0) e2[c] = red[0] + red[1] + red[2] + red[3];
}

// ---------------- pack A: x sem -> 256row x 32K bf16 tiles (chunks: 16 hi, 16 lo) ----------------
// tile byte layout (matches LDS image): off = row*64 + ((u ^ ((row>>1)&3))<<4) + (k&7)*2, u = k>>3
__global__ __launch_bounds__(256) void k_packA(const float* __restrict__ x,
                                               char* __restrict__ Ap) {
    __shared__ char ldsH[16384];
    __shared__ char ldsL[16384];
    int mt = blockIdx.x, dc = blockIdx.y;
    int b = mt >> 4;
    int t0 = (mt & 15) * 256;
    int tid = threadIdx.x;
#pragma unroll
    for (int i = 0; i < 8; i++) {
        int idx = tid + i * 256;
        int d = idx >> 6;            // 0..31
        int t4 = idx & 63;           // 0..63
        float4 v = *(const float4*)&x[((size_t)b * DTOT + dc * 32 + d) * TT_DIM + t0 + t4 * 4];
        float va[4] = {v.x, v.y, v.z, v.w};
        int u = d >> 3;
        int kb = (d & 7) * 2;
#pragma unroll
        for (int j = 0; j < 4; j++) {
            int row = t4 * 4 + j;
            unsigned short hi = f2bf(va[j]);
            unsigned short lo = f2bf(va[j] - bf2f(hi));
            int off = row * 64 + ((u ^ ((row >> 1) & 3)) << 4) + kb;
            *(unsigned short*)&ldsH[off] = hi;
            *(unsigned short*)&ldsL[off] = lo;
        }
    }
    __syncthreads();
    char* gH = Ap + ((size_t)mt * 32 + dc) * 16384;
    char* gL = Ap + ((size_t)mt * 32 + 16 + dc) * 16384;
#pragma unroll
    for (int i = 0; i < 4; i++) {
        int off = (tid + i * 256) * 16;
        *(uint4*)&gH[off] = *(const uint4*)&ldsH[off];
        *(uint4*)&gL[off] = *(const uint4*)&ldsL[off];
    }
}

// ---------------- pack B: emb -> 256code x 32K bf16 tiles (chunks: 16 hi, 16 lo) ----------------
__global__ __launch_bounds__(256) void k_packB(const float* __restrict__ emb,
                                               char* __restrict__ Bp) {
    __shared__ char ldsT[16384];
    int nt = blockIdx.x, c = blockIdx.y;
    int lo_flag = (c >= 16);
    int d0 = (lo_flag ? (c - 16) : c) * 32;
    int c0 = nt * 256;
    int tid = threadIdx.x;
#pragma unroll
    for (int i = 0; i < 8; i++) {
        int idx = tid + i * 256;
        int row = idx >> 3;          // code 0..255
        int f4 = idx & 7;            // d-float4 0..7
        float4 v = *(const float4*)&emb[(size_t)(c0 + row) * DS + d0 + f4 * 4];
        float va[4] = {v.x, v.y, v.z, v.w};
        unsigned short wv[4];
#pragma unroll
        for (int j = 0; j < 4; j++) {
            unsigned short hi = f2bf(va[j]);
            wv[j] = lo_flag ? f2bf(va[j] - bf2f(hi)) : hi;
        }
        int u = f4 >> 1;
        int off = row * 64 + ((u ^ ((row >> 1) & 3)) << 4) + (f4 & 1) * 8;
        uint2 pk;
        pk.x = ((unsigned)wv[1] << 16) | wv[0];
        pk.y = ((unsigned)wv[3] << 16) | wv[2];
        *(uint2*)&ldsT[off] = pk;
    }
    __syncthreads();
    char* g = Bp + ((size_t)nt * 32 + c) * 16384;
#pragma unroll
    for (int i = 0; i < 4; i++) {
        int off = (tid + i * 256) * 16;
        *(uint4*)&g[off] = *(const uint4*)&ldsT[off];
    }
}

// ---------------- MFMA distance-argmin: 256x256 tile, 16 waves x 64x64, BK=64 2-slot dbuf ----------------
// FROZEN from round 14 (869us, MfmaUtil 44.5, VGPR 60, 0 conflicts, passed).
#define MM(A, B, C) __builtin_amdgcn_mfma_f32_16x16x32_bf16((A), (B), (C), 0, 0, 0)

#define GLDS(SRC, DOFF)                                                              \
    __builtin_amdgcn_global_load_lds(                                                \
        (const __attribute__((address_space(1))) void*)(SRC),                        \
        (__attribute__((address_space(3))) void*)&lds[DOFF], 16, 0, 0)

#define BAR __builtin_amdgcn_s_barrier()
#define VMW0 asm volatile("s_waitcnt vmcnt(0)" ::: "memory")
#define VMNONE (void)0

// stage 64-K step T (chunks 2T, 2T+1) into slot (T&1)
#define STAGE64(T) do {                                                              \
    int sb_ = ((T) & 1) * 65536;                                                     \
    _Pragma("unroll")                                                                \
    for (int h_ = 0; h_ < 2; h_++) {                                                 \
        int c_ = 2 * (T) + h_;                                                       \
        int at_ = (c_ < 32) ? (c_ & 15) : (c_ - 16);                                 \
        int bt_ = (c_ < 32) ? c_ : (c_ - 32);                                        \
        GLDS(Ap_mt + at_ * 16384 + t16, sb_ + h_ * 16384 + t16);                     \
        GLDS(Bp_nt + bt_ * 16384 + t16, sb_ + 32768 + h_ * 16384 + t16);             \
    }                                                                                \
} while (0)

// one 64-K step
#define STEP64(T, DO_STG, VMEND, DO_BAR) do {                                        \
    int sb_ = ((T) & 1) * 65536;                                                     \
    bf16x8 bfv[4], af[4];                                                            \
    _Pragma("unroll")                                                                \
    for (int n_ = 0; n_ < 4; n_++)                                                   \
        bfv[n_] = *(const bf16x8*)&lds[sb_ + 32768 + offB[n_]];                      \
    _Pragma("unroll")                                                                \
    for (int m_ = 0; m_ < 4; m_++)                                                   \
        af[m_] = *(const bf16x8*)&lds[sb_ + offA[m_]];                               \
    if (DO_STG) STAGE64((T) + 1);                                                    \
    __builtin_amdgcn_s_setprio(1);                                                   \
    _Pragma("unroll")                                                                \
    for (int m_ = 0; m_ < 4; m_++)                                                   \
        _Pragma("unroll")                                                            \
        for (int n_ = 0; n_ < 4; n_++)                                               \
            acc[m_][n_] = MM(af[m_], bfv[n_], acc[m_][n_]);                          \
    __builtin_amdgcn_s_setprio(0);                                                   \
    _Pragma("unroll")                                                                \
    for (int n_ = 0; n_ < 4; n_++)                                                   \
        bfv[n_] = *(const bf16x8*)&lds[sb_ + 49152 + offB[n_]];                      \
    _Pragma("unroll")                                                                \
    for (int m_ = 0; m_ < 4; m_++)                                                   \
        af[m_] = *(const bf16x8*)&lds[sb_ + 16384 + offA[m_]];                       \
    __builtin_amdgcn_s_setprio(1);                                                   \
    _Pragma("unroll")                                                                \
    for (int m_ = 0; m_ < 4; m_++)                                                   \
        _Pragma("unroll")                                                            \
        for (int n_ = 0; n_ < 4; n_++)                                               \
            acc[m_][n_] = MM(af[m_], bfv[n_], acc[m_][n_]);                          \
    __builtin_amdgcn_s_setprio(0);                                                   \
    VMEND;                                                                           \
    if (DO_BAR) BAR;                                                                 \
} while (0)

__global__ __launch_bounds__(1024, 4) void k_mfma(const char* __restrict__ Ap,
                                                  const char* __restrict__ Bp,
                                                  const float* __restrict__ e2,
                                                  float* __restrict__ pb,
                                                  int* __restrict__ pi,
                                                  float* __restrict__ ps) {
    extern __shared__ char lds[];
    // XCD-bijective swizzle: 4096 blocks, 8 XCDs -> 512 consecutive lin per XCD
    int bid = blockIdx.x;
    int lin = (bid >> 3) + (bid & 7) * 512;
    int nt = lin & 15;
    int mt = lin >> 4;

    int tid = threadIdx.x;
    int lane = tid & 63;
    int w = tid >> 6;            // 0..15
    int wr = w >> 2, wc = w & 3; // 4M x 4N waves, each 64x64
    int l15 = lane & 15, lhi = lane >> 4;
    int t16 = tid * 16;          // 1024 threads x 16B = 16 KB

    const char* Ap_mt = Ap + (size_t)mt * 32 * 16384;
    const char* Bp_nt = Bp + (size_t)nt * 32 * 16384;

    int offA[4], offB[4];
#pragma unroll
    for (int m = 0; m < 4; m++) {
        int r = wr * 64 + m * 16 + l15;
        offA[m] = r * 64 + ((lhi ^ ((r >> 1) & 3)) << 4);
    }
#pragma unroll
    for (int n = 0; n < 4; n++) {
        int r = wc * 64 + n * 16 + l15;
        offB[n] = r * 64 + ((lhi ^ ((r >> 1) & 3)) << 4);
    }

    f32x4 acc[4][4];
#pragma unroll
    for (int m = 0; m < 4; m++)
#pragma unroll
        for (int n = 0; n < 4; n++) acc[m][n] = (f32x4){0.f, 0.f, 0.f, 0.f};

    STAGE64(0);
    VMW0;
    BAR;

#pragma unroll 1
    for (int t = 0; t < 23; t++) {
        STEP64(t, 1, VMW0, 1);
    }
    STEP64(23, 0, VMNONE, 0);

    // ---------------- epilogue: per-row argmin ----------------
    __syncthreads();
    float* rb = (float*)lds;
    float* rs = (float*)(lds + 4096);
    int*   ri = (int*)(lds + 8192);

    float e2v[4];
#pragma unroll
    for (int n = 0; n < 4; n++)
        e2v[n] = e2[nt * 256 + wc * 64 + n * 16 + l15];

#pragma unroll
    for (int m = 0; m < 4; m++) {
#pragma unroll
        for (int r2 = 0; r2 < 4; r2++) {
            float bst = 3.4e38f, sec = 3.4e38f;
            int bi = 1 << 30;
#pragma unroll
            for (int n = 0; n < 4; n++) {
                float v = e2v[n] - 2.f * acc[m][n][r2];
                int vi = wc * 64 + n * 16 + l15;
                if (v < bst || (v == bst && vi < bi)) { sec = bst; bst = v; bi = vi; }
                else sec = fminf(sec, v);
            }
#pragma unroll
            for (int mask = 1; mask <= 8; mask <<= 1) {
                float ob = __shfl_xor(bst, mask);
                int obi = __shfl_xor(bi, mask);
                float os = __shfl_xor(sec, mask);
                if (ob < bst || (ob == bst && obi < bi)) {
                    sec = fminf(bst, os); bst = ob; bi = obi;
                } else {
                    sec = fminf(sec, ob);
                }
            }
            if (l15 == 0) {
                int rl = wr * 64 + m * 16 + lhi * 4 + r2;
                int slot = wc * 256 + rl;
                rb[slot] = bst; rs[slot] = sec; ri[slot] = nt * 256 + bi;
            }
        }
    }
    __syncthreads();
    if (tid < 256) {
        float bsv = rb[tid], ssv = rs[tid];
        int biv = ri[tid];
#pragma unroll
        for (int c = 1; c < 4; c++) {
            float ob = rb[c * 256 + tid];
            float os = rs[c * 256 + tid];
            int oi = ri[c * 256 + tid];
            if (ob < bsv || (ob == bsv && oi < biv)) { ssv = fminf(bsv, os); bsv = ob; biv = oi; }
            else ssv = fminf(ssv, ob);
        }
        size_t gr = (size_t)mt * 256 + tid;
        pb[(size_t)nt * NROWS + gr] = bsv;
        pi[(size_t)nt * NROWS + gr] = biv;
        ps[(size_t)nt * NROWS + gr] = ssv;
    }
}

// ---------------- reduce partials -> codes + flagged rows ----------------
__global__ __launch_bounds__(256) void k_reduce(const float* __restrict__ pb,
                                                const int* __restrict__ pi,
                                                const float* __restrict__ ps,
                                                int* __restrict__ codes,
                                                int* __restrict__ list,
                                                int* __restrict__ counter) {
    int row = blockIdx.x * 256 + threadIdx.x;
    float b = 3.4e38f, s = 3.4e38f;
    int bi = 1 << 30;
    for (int nt = 0; nt < NT; nt++) {
        float b2 = pb[(size_t)nt * NROWS + row];
        int i2 = pi[(size_t)nt * NROWS + row];
        float s2 = ps[(size_t)nt * NROWS + row];
        if (b2 < b || (b2 == b && i2 < bi)) { s = fminf(b, s2); b = b2; bi = i2; }
        else s = fminf(s, b2);
    }
    codes[row] = bi;
    if (s - b < REFINE_THR) {
        int p = atomicAdd(counter, 1);
        list[p] = row;
    }
}

// ---------------- fp64 full-scan refine of flagged rows ----------------
__global__ __launch_bounds__(256) void k_refine(const float* __restrict__ x,
                                                const float* __restrict__ emb,
                                                int* __restrict__ codes,
                                                const int* __restrict__ list,
                                                const int* __restrict__ counter) {
    __shared__ float xrow[DS];
    __shared__ double redv[256];
    __shared__ int redi[256];
    int tid = threadIdx.x;
    int nflag = *counter;
    for (int it = blockIdx.x; it < nflag; it += gridDim.x) {
        int row = list[it];
        int b = row >> 12;
        int t = row & 4095;
        for (int d = tid; d < DS; d += 256)
            xrow[d] = x[((size_t)b * DTOT + d) * TT_DIM + t];
        __syncthreads();
        double bv = 1e300;
        int bi = 1 << 30;
        for (int c = tid; c < NCODES; c += 256) {
            const float* er = emb + (size_t)c * DS;
            double s = 0.0;
            for (int d = 0; d < DS; d += 4) {
                float4 ev = *(const float4*)&er[d];
                float4 xv = *(const float4*)&xrow[d];
                double d0 = (double)xv.x - (double)ev.x;
                double d1 = (double)xv.y - (double)ev.y;
                double d2 = (double)xv.z - (double)ev.z;
                double d3 = (double)xv.w - (double)ev.w;
                s += d0 * d0 + d1 * d1 + d2 * d2 + d3 * d3;
            }
            if (s < bv || (s == bv && c < bi)) { bv = s; bi = c; }
        }
        redv[tid] = bv; redi[tid] = bi;
        __syncthreads();
        for (int off = 128; off; off >>= 1) {
            if (tid < off) {
                if (redv[tid + off] < redv[tid] ||
                    (redv[tid + off] == redv[tid] && redi[tid + off] < redi[tid])) {
                    redv[tid] = redv[tid + off];
                    redi[tid] = redi[tid + off];
                }
            }
            __syncthreads();
        }
        if (tid == 0) codes[row] = redi[0];
        __syncthreads();
    }
}

// ---------------- sem output: vectorized gather (register 4x4 transpose) or float4 copy ----------------
__global__ __launch_bounds__(256) void k_sem(const float* __restrict__ x,
                                             const float* __restrict__ emb,
                                             const int* __restrict__ codes,
                                             const float* __restrict__ sem_probs,
                                             float* __restrict__ out) {
    __shared__ int rowc[TT];
    int b = blockIdx.y, t0 = blockIdx.x * TT;
    bool mask = sem_probs[b] < 0.5f;
    float* outb = out + (size_t)b * DTOT * TT_DIM + t0;
    const float* xb = x + (size_t)b * DTOT * TT_DIM + t0;
    const size_t QOFF = (size_t)BB * DTOT * TT_DIM;

    if (threadIdx.x < TT) {
        int code = codes[b * TT_DIM + t0 + threadIdx.x];
        rowc[threadIdx.x] = code;
        out[QOFF + ((size_t)b * 33) * TT_DIM + t0 + threadIdx.x] = (float)code;
    }
    __syncthreads();

    if (mask) {
        // thread unit (d4, tg): gather 4 emb float4 (4 code rows, same d4),
        // 4x4 register transpose, 4 coalesced float4 stores over t.
#pragma unroll
        for (int i = 0; i < 4; i++) {
            int u = threadIdx.x + i * 256;   // 0..1023
            int d4 = u >> 3;                 // 0..127
            int tg = u & 7;                  // 0..7
            float4 r0 = *(const float4*)&emb[(size_t)rowc[tg * 4 + 0] * DS + d4 * 4];
            float4 r1 = *(const float4*)&emb[(size_t)rowc[tg * 4 + 1] * DS + d4 * 4];
            float4 r2 = *(const float4*)&emb[(size_t)rowc[tg * 4 + 2] * DS + d4 * 4];
            float4 r3 = *(const float4*)&emb[(size_t)rowc[tg * 4 + 3] * DS + d4 * 4];
            float4 c0 = {r0.x, r1.x, r2.x, r3.x};
            float4 c1 = {r0.y, r1.y, r2.y, r3.y};
            float4 c2 = {r0.z, r1.z, r2.z, r3.z};
            float4 c3 = {r0.w, r1.w, r2.w, r3.w};
            *(float4*)&outb[(size_t)(d4 * 4 + 0) * TT_DIM + tg * 4] = c0;
            *(float4*)&outb[(size_t)(d4 * 4 + 1) * TT_DIM + tg * 4] = c1;
            *(float4*)&outb[(size_t)(d4 * 4 + 2) * TT_DIM + tg * 4] = c2;
            *(float4*)&outb[(size_t)(d4 * 4 + 3) * TT_DIM + tg * 4] = c3;
        }
    } else {
#pragma unroll
        for (int i = 0; i < 16; i++) {
            int u = threadIdx.x + i * 256;   // 0..4095
            int d = u >> 3;                  // 0..511
            int tg = u & 7;
            *(float4*)&outb[(size_t)d * TT_DIM + tg * 4] =
                *(const float4*)&xb[(size_t)d * TT_DIM + tg * 4];
        }
    }
}

// ---------------- aco elementwise ----------------
__global__ __launch_bounds__(256) void k_aco(const float* __restrict__ x,
                                             const float* __restrict__ noise,
                                             const float* __restrict__ aco_probs,
                                             float* __restrict__ out) {
    int idx = blockIdx.x * 256 + threadIdx.x;
    int t4 = idx & 1023;
    int bc = idx >> 10;
    int ch = bc & 31;
    int b = bc >> 5;
    const float4 xv = *(const float4*)&x[((size_t)(b * DTOT + DS + ch)) * TT_DIM + t4 * 4];
    const float4 nv = *(const float4*)&noise[((size_t)(b * 32 + ch)) * TT_DIM + t4 * 4];
    float p = aco_probs[b];
    const size_t QOFF = (size_t)BB * DTOT * TT_DIM;

    float zq[4], cq[4];
    float xa[4] = {xv.x, xv.y, xv.z, xv.w};
    float na[4] = {nv.x, nv.y, nv.z, nv.w};
#pragma unroll
    for (int i = 0; i < 4; i++) {
        float zb = tanhf(xa[i]) * HALFV;
        float z;
        if (p < 0.5f) z = rintf(zb);
        else if (p < 0.75f) z = fminf(fmaxf(zb + na[i], -HALFV), HALFV);
        else z = zb;
        zq[i] = z / HALFV;
        cq[i] = fminf(fmaxf(rintf(z + HALFV), 0.f), 15.f);
    }
    float4 qo = {zq[0], zq[1], zq[2], zq[3]};
    float4 co = {cq[0], cq[1], cq[2], cq[3]};
    *(float4*)&out[((size_t)(b * DTOT + DS + ch)) * TT_DIM + t4 * 4] = qo;
    *(float4*)&out[QOFF + ((size_t)(b * 33 + 1 + ch)) * TT_DIM + t4 * 4] = co;
}

extern "C" void kernel_launch(void* const* d_in, const int* in_sizes, int n_in,
                              void* d_out, int out_size, void* d_ws, size_t ws_size,
                              hipStream_t stream) {
    const float* x         = (const float*)d_in[0];
    const float* esum      = (const float*)d_in[1];
    const float* usage     = (const float*)d_in[2];
    const float* sem_probs = (const float*)d_in[3];
    const float* aco_probs = (const float*)d_in[4];
    const float* noise     = (const float*)d_in[5];
    float* out = (float*)d_out;

    char* w = (char*)d_ws;
    float* emb    = (float*)w;                         // 8,388,608
    float* e2     = (float*)(w + 8388608);             // 16,384
    char*  Ap     = w + 8404992;                       // 134,217,728
    char*  Bp     = w + 142622720;                     // 8,388,608
    float* pb     = (float*)(w + 151011328);           // 4,194,304
    int*   pi     = (int*)(w + 155205632);             // 4,194,304
    float* ps     = (float*)(w + 159399936);           // 4,194,304
    int*   codes  = (int*)(w + 163594240);             // 262,144
    int*   list   = (int*)(w + 163856384);             // 262,144
    int*   counter= (int*)(w + 164118528);             // 4

    k_emb<<<NCODES, 256, 0, stream>>>(esum, usage, emb, e2, counter);
    k_packA<<<dim3(MT, 16), 256, 0, stream>>>(x, Ap);
    k_packB<<<dim3(NT, 32), 256, 0, stream>>>(emb, Bp);
    k_mfma<<<NT * MT, 1024, 131072, stream>>>(Ap, Bp, e2, pb, pi, ps);
    k_reduce<<<NROWS / 256, 256, 0, stream>>>(pb, pi, ps, codes, list, counter);
    k_refine<<<256, 256, 0, stream>>>(x, emb, codes, list, counter);
    k_sem<<<dim3(TT_DIM / TT, BB), 256, 0, stream>>>(x, emb, codes, sem_probs, out);
    k_aco<<<(BB * 32 * TT_DIM) / (256 * 4), 256, 0, stream>>>(x, noise, aco_probs, out);
}

// Round 16
// 1086.094 us; speedup vs baseline: 9.8408x; 1.0784x over previous
//
#include <hip/hip_runtime.h>
#include <math.h>

#define BB 16
#define DTOT 544
#define TT_DIM 4096
#define DS 512
#define NCODES 4096
#define HALFV 7.5f
#define EPSV 1e-5f
#define NROWS (BB * TT_DIM)          // 65536
#define NT 16                        // 4096 / 256
#define MT 256                       // 65536 / 256
#define REFINE_THR 0.01f
#define TT 32                        // t per block in k_sem

typedef short bf16x8 __attribute__((ext_vector_type(8)));
typedef float f32x4 __attribute__((ext_vector_type(4)));

__device__ __forceinline__ unsigned short f2bf(float v) {
    unsigned u = __float_as_uint(v);
    unsigned r = (u + 0x7fffu + ((u >> 16) & 1u)) >> 16;
    return (unsigned short)r;
}
__device__ __forceinline__ float bf2f(unsigned short h) {
    return __uint_as_float((unsigned)h << 16);
}

// ---------------- kernel: emb fp32 + e2 + zero flag counter ----------------
__global__ __launch_bounds__(256) void k_emb(const float* __restrict__ esum,
                                             const float* __restrict__ usage,
                                             float* __restrict__ emb,
                                             float* __restrict__ e2,
                                             int* __restrict__ counter) {
    int c = blockIdx.x;
    if (c == 0 && threadIdx.x == 0) *counter = 0;
    float u = usage[c];
    u = (u < EPSV) ? EPSV : u;
    float s = 0.f;
#pragma unroll
    for (int i = 0; i < 2; i++) {
        int d = threadIdx.x + i * 256;
        float v = esum[(size_t)c * DS + d] / u;
        emb[(size_t)c * DS + d] = v;
        s += v * v;
    }
#pragma unroll
    for (int o = 32; o; o >>= 1) s += __shfl_down(s, o, 64);
    __shared__ float red[4];
    if ((threadIdx.x & 63) == 0) red[threadIdx.x >> 6] = s;
    __syncthreads();
    if (threadIdx.x == 0) e2[c] = red[0] + red[1] + red[2] + red[3];
}

// ---------------- pack A: x sem -> 256row x 32K bf16 tiles (chunks: 16 hi, 16 lo) ----------------
// tile byte layout (matches LDS image): off = row*64 + ((u ^ ((row>>1)&3))<<4) + (k&7)*2, u = k>>3
__global__ __launch_bounds__(256) void k_packA(const float* __restrict__ x,
                                               char* __restrict__ Ap) {
    __shared__ char ldsH[16384];
    __shared__ char ldsL[16384];
    int mt = blockIdx.x, dc = blockIdx.y;
    int b = mt >> 4;
    int t0 = (mt & 15) * 256;
    int tid = threadIdx.x;
#pragma unroll
    for (int i = 0; i < 8; i++) {
        int idx = tid + i * 256;
        int d = idx >> 6;            // 0..31
        int t4 = idx & 63;           // 0..63
        float4 v = *(const float4*)&x[((size_t)b * DTOT + dc * 32 + d) * TT_DIM + t0 + t4 * 4];
        float va[4] = {v.x, v.y, v.z, v.w};
        int u = d >> 3;
        int kb = (d & 7) * 2;
#pragma unroll
        for (int j = 0; j < 4; j++) {
            int row = t4 * 4 + j;
            unsigned short hi = f2bf(va[j]);
            unsigned short lo = f2bf(va[j] - bf2f(hi));
            int off = row * 64 + ((u ^ ((row >> 1) & 3)) << 4) + kb;
            *(unsigned short*)&ldsH[off] = hi;
            *(unsigned short*)&ldsL[off] = lo;
        }
    }
    __syncthreads();
    char* gH = Ap + ((size_t)mt * 32 + dc) * 16384;
    char* gL = Ap + ((size_t)mt * 32 + 16 + dc) * 16384;
#pragma unroll
    for (int i = 0; i < 4; i++) {
        int off = (tid + i * 256) * 16;
        *(uint4*)&gH[off] = *(const uint4*)&ldsH[off];
        *(uint4*)&gL[off] = *(const uint4*)&ldsL[off];
    }
}

// ---------------- pack B: emb -> 256code x 32K bf16 tiles (chunks: 16 hi, 16 lo) ----------------
__global__ __launch_bounds__(256) void k_packB(const float* __restrict__ emb,
                                               char* __restrict__ Bp) {
    __shared__ char ldsT[16384];
    int nt = blockIdx.x, c = blockIdx.y;
    int lo_flag = (c >= 16);
    int d0 = (lo_flag ? (c - 16) : c) * 32;
    int c0 = nt * 256;
    int tid = threadIdx.x;
#pragma unroll
    for (int i = 0; i < 8; i++) {
        int idx = tid + i * 256;
        int row = idx >> 3;          // code 0..255
        int f4 = idx & 7;            // d-float4 0..7
        float4 v = *(const float4*)&emb[(size_t)(c0 + row) * DS + d0 + f4 * 4];
        float va[4] = {v.x, v.y, v.z, v.w};
        unsigned short wv[4];
#pragma unroll
        for (int j = 0; j < 4; j++) {
            unsigned short hi = f2bf(va[j]);
            wv[j] = lo_flag ? f2bf(va[j] - bf2f(hi)) : hi;
        }
        int u = f4 >> 1;
        int off = row * 64 + ((u ^ ((row >> 1) & 3)) << 4) + (f4 & 1) * 8;
        uint2 pk;
        pk.x = ((unsigned)wv[1] << 16) | wv[0];
        pk.y = ((unsigned)wv[3] << 16) | wv[2];
        *(uint2*)&ldsT[off] = pk;
    }
    __syncthreads();
    char* g = Bp + ((size_t)nt * 32 + c) * 16384;
#pragma unroll
    for (int i = 0; i < 4; i++) {
        int off = (tid + i * 256) * 16;
        *(uint4*)&g[off] = *(const uint4*)&ldsT[off];
    }
}

// ---------------- MFMA distance-argmin: 256x256 tile, 16 waves x 64x64, BK=64 2-slot dbuf ----------------
// Main loop FROZEN from round 14 (869us, MfmaUtil 44.5, VGPR 60, 0 conflicts, passed).
// Epilogue extended: second-best INDEX tracked (enables 2-candidate fp64 refine).
#define MM(A, B, C) __builtin_amdgcn_mfma_f32_16x16x32_bf16((A), (B), (C), 0, 0, 0)

#define GLDS(SRC, DOFF)                                                              \
    __builtin_amdgcn_global_load_lds(                                                \
        (const __attribute__((address_space(1))) void*)(SRC),                        \
        (__attribute__((address_space(3))) void*)&lds[DOFF], 16, 0, 0)

#define BAR __builtin_amdgcn_s_barrier()
#define VMW0 asm volatile("s_waitcnt vmcnt(0)" ::: "memory")
#define VMNONE (void)0

// stage 64-K step T (chunks 2T, 2T+1) into slot (T&1)
#define STAGE64(T) do {                                                              \
    int sb_ = ((T) & 1) * 65536;                                                     \
    _Pragma("unroll")                                                                \
    for (int h_ = 0; h_ < 2; h_++) {                                                 \
        int c_ = 2 * (T) + h_;                                                       \
        int at_ = (c_ < 32) ? (c_ & 15) : (c_ - 16);                                 \
        int bt_ = (c_ < 32) ? c_ : (c_ - 32);                                        \
        GLDS(Ap_mt + at_ * 16384 + t16, sb_ + h_ * 16384 + t16);                     \
        GLDS(Bp_nt + bt_ * 16384 + t16, sb_ + 32768 + h_ * 16384 + t16);             \
    }                                                                                \
} while (0)

// one 64-K step
#define STEP64(T, DO_STG, VMEND, DO_BAR) do {                                        \
    int sb_ = ((T) & 1) * 65536;                                                     \
    bf16x8 bfv[4], af[4];                                                            \
    _Pragma("unroll")                                                                \
    for (int n_ = 0; n_ < 4; n_++)                                                   \
        bfv[n_] = *(const bf16x8*)&lds[sb_ + 32768 + offB[n_]];                      \
    _Pragma("unroll")                                                                \
    for (int m_ = 0; m_ < 4; m_++)                                                   \
        af[m_] = *(const bf16x8*)&lds[sb_ + offA[m_]];                               \
    if (DO_STG) STAGE64((T) + 1);                                                    \
    __builtin_amdgcn_s_setprio(1);                                                   \
    _Pragma("unroll")                                                                \
    for (int m_ = 0; m_ < 4; m_++)                                                   \
        _Pragma("unroll")                                                            \
        for (int n_ = 0; n_ < 4; n_++)                                               \
            acc[m_][n_] = MM(af[m_], bfv[n_], acc[m_][n_]);                          \
    __builtin_amdgcn_s_setprio(0);                                                   \
    _Pragma("unroll")                                                                \
    for (int n_ = 0; n_ < 4; n_++)                                                   \
        bfv[n_] = *(const bf16x8*)&lds[sb_ + 49152 + offB[n_]];                      \
    _Pragma("unroll")                                                                \
    for (int m_ = 0; m_ < 4; m_++)                                                   \
        af[m_] = *(const bf16x8*)&lds[sb_ + 16384 + offA[m_]];                       \
    __builtin_amdgcn_s_setprio(1);                                                   \
    _Pragma("unroll")                                                                \
    for (int m_ = 0; m_ < 4; m_++)                                                   \
        _Pragma("unroll")                                                            \
        for (int n_ = 0; n_ < 4; n_++)                                               \
            acc[m_][n_] = MM(af[m_], bfv[n_], acc[m_][n_]);                          \
    __builtin_amdgcn_s_setprio(0);                                                   \
    VMEND;                                                                           \
    if (DO_BAR) BAR;                                                                 \
} while (0)

__global__ __launch_bounds__(1024, 4) void k_mfma(const char* __restrict__ Ap,
                                                  const char* __restrict__ Bp,
                                                  const float* __restrict__ e2,
                                                  float* __restrict__ pb,
                                                  int* __restrict__ pi,
                                                  float* __restrict__ ps,
                                                  int* __restrict__ psi) {
    extern __shared__ char lds[];
    // XCD-bijective swizzle: 4096 blocks, 8 XCDs -> 512 consecutive lin per XCD
    int bid = blockIdx.x;
    int lin = (bid >> 3) + (bid & 7) * 512;
    int nt = lin & 15;
    int mt = lin >> 4;

    int tid = threadIdx.x;
    int lane = tid & 63;
    int w = tid >> 6;            // 0..15
    int wr = w >> 2, wc = w & 3; // 4M x 4N waves, each 64x64
    int l15 = lane & 15, lhi = lane >> 4;
    int t16 = tid * 16;          // 1024 threads x 16B = 16 KB

    const char* Ap_mt = Ap + (size_t)mt * 32 * 16384;
    const char* Bp_nt = Bp + (size_t)nt * 32 * 16384;

    int offA[4], offB[4];
#pragma unroll
    for (int m = 0; m < 4; m++) {
        int r = wr * 64 + m * 16 + l15;
        offA[m] = r * 64 + ((lhi ^ ((r >> 1) & 3)) << 4);
    }
#pragma unroll
    for (int n = 0; n < 4; n++) {
        int r = wc * 64 + n * 16 + l15;
        offB[n] = r * 64 + ((lhi ^ ((r >> 1) & 3)) << 4);
    }

    f32x4 acc[4][4];
#pragma unroll
    for (int m = 0; m < 4; m++)
#pragma unroll
        for (int n = 0; n < 4; n++) acc[m][n] = (f32x4){0.f, 0.f, 0.f, 0.f};

    STAGE64(0);
    VMW0;
    BAR;

#pragma unroll 1
    for (int t = 0; t < 23; t++) {
        STEP64(t, 1, VMW0, 1);
    }
    STEP64(23, 0, VMNONE, 0);

    // ---------------- epilogue: per-row argmin with second-best index ----------------
    __syncthreads();
    float* rb = (float*)lds;
    float* rs = (float*)(lds + 4096);
    int*   ri = (int*)(lds + 8192);
    int*   rsi = (int*)(lds + 12288);

    float e2v[4];
#pragma unroll
    for (int n = 0; n < 4; n++)
        e2v[n] = e2[nt * 256 + wc * 64 + n * 16 + l15];

#pragma unroll
    for (int m = 0; m < 4; m++) {
#pragma unroll
        for (int r2 = 0; r2 < 4; r2++) {
            float bst = 3.4e38f, sec = 3.4e38f;
            int bi = 1 << 30, si = 1 << 30;
#pragma unroll
            for (int n = 0; n < 4; n++) {
                float v = e2v[n] - 2.f * acc[m][n][r2];
                int vi = wc * 64 + n * 16 + l15;
                if (v < bst || (v == bst && vi < bi)) { sec = bst; si = bi; bst = v; bi = vi; }
                else if (v < sec || (v == sec && vi < si)) { sec = v; si = vi; }
            }
#pragma unroll
            for (int mask = 1; mask <= 8; mask <<= 1) {
                float ob = __shfl_xor(bst, mask);
                int obi = __shfl_xor(bi, mask);
                float os = __shfl_xor(sec, mask);
                int osi = __shfl_xor(si, mask);
                if (ob < bst || (ob == bst && obi < bi)) {
                    if (bst < os || (bst == os && bi < osi)) { sec = bst; si = bi; }
                    else { sec = os; si = osi; }
                    bst = ob; bi = obi;
                } else {
                    if (ob < sec || (ob == sec && obi < si)) { sec = ob; si = obi; }
                }
            }
            if (l15 == 0) {
                int rl = wr * 64 + m * 16 + lhi * 4 + r2;
                int slot = wc * 256 + rl;
                rb[slot] = bst; rs[slot] = sec;
                ri[slot] = nt * 256 + bi; rsi[slot] = nt * 256 + si;
            }
        }
    }
    __syncthreads();
    if (tid < 256) {
        float bsv = rb[tid], ssv = rs[tid];
        int biv = ri[tid], siv = rsi[tid];
#pragma unroll
        for (int c = 1; c < 4; c++) {
            float ob = rb[c * 256 + tid];
            float os = rs[c * 256 + tid];
            int oi = ri[c * 256 + tid];
            int osi = rsi[c * 256 + tid];
            if (ob < bsv || (ob == bsv && oi < biv)) {
                if (bsv < os || (bsv == os && biv < osi)) { ssv = bsv; siv = biv; }
                else { ssv = os; siv = osi; }
                bsv = ob; biv = oi;
            } else {
                if (ob < ssv || (ob == ssv && oi < siv)) { ssv = ob; siv = oi; }
            }
        }
        size_t gr = (size_t)mt * 256 + tid;
        pb[(size_t)nt * NROWS + gr] = bsv;
        pi[(size_t)nt * NROWS + gr] = biv;
        ps[(size_t)nt * NROWS + gr] = ssv;
        psi[(size_t)nt * NROWS + gr] = siv;
    }
}

// ---------------- reduce partials -> codes + cand2 + flagged rows ----------------
__global__ __launch_bounds__(256) void k_reduce(const float* __restrict__ pb,
                                                const int* __restrict__ pi,
                                                const float* __restrict__ ps,
                                                const int* __restrict__ psi,
                                                int* __restrict__ codes,
                                                int* __restrict__ cand2,
                                                int* __restrict__ list,
                                                int* __restrict__ counter) {
    int row = blockIdx.x * 256 + threadIdx.x;
    float b = 3.4e38f, s = 3.4e38f;
    int bi = 1 << 30, si = 1 << 30;
    for (int nt = 0; nt < NT; nt++) {
        float b2 = pb[(size_t)nt * NROWS + row];
        int i2 = pi[(size_t)nt * NROWS + row];
        float s2 = ps[(size_t)nt * NROWS + row];
        int si2 = psi[(size_t)nt * NROWS + row];
        if (b2 < b || (b2 == b && i2 < bi)) {
            if (b < s2 || (b == s2 && bi < si2)) { s = b; si = bi; }
            else { s = s2; si = si2; }
            b = b2; bi = i2;
        } else {
            if (b2 < s || (b2 == s && i2 < si)) { s = b2; si = i2; }
        }
    }
    codes[row] = bi;
    cand2[row] = si;
    if (s - b < REFINE_THR) {
        int p = atomicAdd(counter, 1);
        list[p] = row;
    }
}

// ---------------- fp64 2-candidate refine of flagged rows (one wave per row) ----------------
__global__ __launch_bounds__(256) void k_refine(const float* __restrict__ x,
                                                const float* __restrict__ emb,
                                                int* __restrict__ codes,
                                                const int* __restrict__ cand2,
                                                const int* __restrict__ list,
                                                const int* __restrict__ counter) {
    int wid = threadIdx.x >> 6, lane = threadIdx.x & 63;
    int nflag = *counter;
    for (int it = blockIdx.x * 4 + wid; it < nflag; it += gridDim.x * 4) {
        int row = list[it];
        int b = row >> 12;
        int t = row & 4095;
        int c1 = codes[row], c2 = cand2[row];
        if (c2 >= NCODES) continue;
        const float* xb = x + (size_t)b * DTOT * TT_DIM + t;
        double s1 = 0.0, s2 = 0.0;
        for (int d = lane; d < DS; d += 64) {
            double xv = (double)xb[(size_t)d * TT_DIM];
            double d1 = xv - (double)emb[(size_t)c1 * DS + d];
            double d2v = xv - (double)emb[(size_t)c2 * DS + d];
            s1 += d1 * d1;
            s2 += d2v * d2v;
        }
#pragma unroll
        for (int o = 32; o; o >>= 1) {
            s1 += __shfl_down(s1, o, 64);
            s2 += __shfl_down(s2, o, 64);
        }
        if (lane == 0) {
            if (s2 < s1 || (s2 == s1 && c2 < c1)) codes[row] = c2;
        }
    }
}

// ---------------- sem output: vectorized gather (register 4x4 transpose) or float4 copy ----------------
__global__ __launch_bounds__(256) void k_sem(const float* __restrict__ x,
                                             const float* __restrict__ emb,
                                             const int* __restrict__ codes,
                                             const float* __restrict__ sem_probs,
                                             float* __restrict__ out) {
    __shared__ int rowc[TT];
    int b = blockIdx.y, t0 = blockIdx.x * TT;
    bool mask = sem_probs[b] < 0.5f;
    float* outb = out + (size_t)b * DTOT * TT_DIM + t0;
    const float* xb = x + (size_t)b * DTOT * TT_DIM + t0;
    const size_t QOFF = (size_t)BB * DTOT * TT_DIM;

    if (threadIdx.x < TT) {
        int code = codes[b * TT_DIM + t0 + threadIdx.x];
        rowc[threadIdx.x] = code;
        out[QOFF + ((size_t)b * 33) * TT_DIM + t0 + threadIdx.x] = (float)code;
    }
    __syncthreads();

    if (mask) {
#pragma unroll
        for (int i = 0; i < 4; i++) {
            int u = threadIdx.x + i * 256;   // 0..1023
            int d4 = u >> 3;                 // 0..127
            int tg = u & 7;                  // 0..7
            float4 r0 = *(const float4*)&emb[(size_t)rowc[tg * 4 + 0] * DS + d4 * 4];
            float4 r1 = *(const float4*)&emb[(size_t)rowc[tg * 4 + 1] * DS + d4 * 4];
            float4 r2 = *(const float4*)&emb[(size_t)rowc[tg * 4 + 2] * DS + d4 * 4];
            float4 r3 = *(const float4*)&emb[(size_t)rowc[tg * 4 + 3] * DS + d4 * 4];
            float4 c0 = {r0.x, r1.x, r2.x, r3.x};
            float4 c1 = {r0.y, r1.y, r2.y, r3.y};
            float4 c2 = {r0.z, r1.z, r2.z, r3.z};
            float4 c3 = {r0.w, r1.w, r2.w, r3.w};
            *(float4*)&outb[(size_t)(d4 * 4 + 0) * TT_DIM + tg * 4] = c0;
            *(float4*)&outb[(size_t)(d4 * 4 + 1) * TT_DIM + tg * 4] = c1;
            *(float4*)&outb[(size_t)(d4 * 4 + 2) * TT_DIM + tg * 4] = c2;
            *(float4*)&outb[(size_t)(d4 * 4 + 3) * TT_DIM + tg * 4] = c3;
        }
    } else {
#pragma unroll
        for (int i = 0; i < 16; i++) {
            int u = threadIdx.x + i * 256;   // 0..4095
            int d = u >> 3;                  // 0..511
            int tg = u & 7;
            *(float4*)&outb[(size_t)d * TT_DIM + tg * 4] =
                *(const float4*)&xb[(size_t)d * TT_DIM + tg * 4];
        }
    }
}

// ---------------- aco elementwise ----------------
__global__ __launch_bounds__(256) void k_aco(const float* __restrict__ x,
                                             const float* __restrict__ noise,
                                             const float* __restrict__ aco_probs,
                                             float* __restrict__ out) {
    int idx = blockIdx.x * 256 + threadIdx.x;
    int t4 = idx & 1023;
    int bc = idx >> 10;
    int ch = bc & 31;
    int b = bc >> 5;
    const float4 xv = *(const float4*)&x[((size_t)(b * DTOT + DS + ch)) * TT_DIM + t4 * 4];
    const float4 nv = *(const float4*)&noise[((size_t)(b * 32 + ch)) * TT_DIM + t4 * 4];
    float p = aco_probs[b];
    const size_t QOFF = (size_t)BB * DTOT * TT_DIM;

    float zq[4], cq[4];
    float xa[4] = {xv.x, xv.y, xv.z, xv.w};
    float na[4] = {nv.x, nv.y, nv.z, nv.w};
#pragma unroll
    for (int i = 0; i < 4; i++) {
        float zb = tanhf(xa[i]) * HALFV;
        float z;
        if (p < 0.5f) z = rintf(zb);
        else if (p < 0.75f) z = fminf(fmaxf(zb + na[i], -HALFV), HALFV);
        else z = zb;
        zq[i] = z / HALFV;
        cq[i] = fminf(fmaxf(rintf(z + HALFV), 0.f), 15.f);
    }
    float4 qo = {zq[0], zq[1], zq[2], zq[3]};
    float4 co = {cq[0], cq[1], cq[2], cq[3]};
    *(float4*)&out[((size_t)(b * DTOT + DS + ch)) * TT_DIM + t4 * 4] = qo;
    *(float4*)&out[QOFF + ((size_t)(b * 33 + 1 + ch)) * TT_DIM + t4 * 4] = co;
}

extern "C" void kernel_launch(void* const* d_in, const int* in_sizes, int n_in,
                              void* d_out, int out_size, void* d_ws, size_t ws_size,
                              hipStream_t stream) {
    const float* x         = (const float*)d_in[0];
    const float* esum      = (const float*)d_in[1];
    const float* usage     = (const float*)d_in[2];
    const float* sem_probs = (const float*)d_in[3];
    const float* aco_probs = (const float*)d_in[4];
    const float* noise     = (const float*)d_in[5];
    float* out = (float*)d_out;

    char* w = (char*)d_ws;
    float* emb    = (float*)w;                         // 8,388,608
    float* e2     = (float*)(w + 8388608);             // 16,384
    char*  Ap     = w + 8404992;                       // 134,217,728
    char*  Bp     = w + 142622720;                     // 8,388,608
    float* pb     = (float*)(w + 151011328);           // 4,194,304
    int*   pi     = (int*)(w + 155205632);             // 4,194,304
    float* ps     = (float*)(w + 159399936);           // 4,194,304
    int*   psi    = (int*)(w + 163594240);             // 4,194,304
    int*   codes  = (int*)(w + 167788544);             // 262,144
    int*   cand2  = (int*)(w + 168050688);             // 262,144
    int*   list   = (int*)(w + 168312832);             // 262,144
    int*   counter= (int*)(w + 168574976);             // 4

    k_emb<<<NCODES, 256, 0, stream>>>(esum, usage, emb, e2, counter);
    k_packA<<<dim3(MT, 16), 256, 0, stream>>>(x, Ap);
    k_packB<<<dim3(NT, 32), 256, 0, stream>>>(emb, Bp);
    k_mfma<<<NT * MT, 1024, 131072, stream>>>(Ap, Bp, e2, pb, pi, ps, psi);
    k_reduce<<<NROWS / 256, 256, 0, stream>>>(pb, pi, ps, psi, codes, cand2, list, counter);
    k_refine<<<256, 256, 0, stream>>>(x, emb, codes, cand2, list, counter);
    k_sem<<<dim3(TT_DIM / TT, BB), 256, 0, stream>>>(x, emb, codes, sem_probs, out);
    k_aco<<<(BB * 32 * TT_DIM) / (256 * 4), 256, 0, stream>>>(x, noise, aco_probs, out);
}

// Round 17
// 1005.633 us; speedup vs baseline: 10.6282x; 1.0800x over previous
//
#include <hip/hip_runtime.h>
#include <math.h>

#define BB 16
#define DTOT 544
#define TT_DIM 4096
#define DS 512
#define NCODES 4096
#define HALFV 7.5f
#define EPSV 1e-5f
#define NROWS (BB * TT_DIM)          // 65536
#define NT 16                        // 4096 / 256
#define MT 256                       // 65536 / 256
#define REFINE_THR 0.01f
#define TT 32                        // t per block in k_sem

typedef short bf16x8 __attribute__((ext_vector_type(8)));
typedef float f32x4 __attribute__((ext_vector_type(4)));

__device__ __forceinline__ unsigned short f2bf(float v) {
    unsigned u = __float_as_uint(v);
    unsigned r = (u + 0x7fffu + ((u >> 16) & 1u)) >> 16;
    return (unsigned short)r;
}
__device__ __forceinline__ float bf2f(unsigned short h) {
    return __uint_as_float((unsigned)h << 16);
}

// ---------------- kernel: emb fp32 + e2 + zero flag counter ----------------
__global__ __launch_bounds__(256) void k_emb(const float* __restrict__ esum,
                                             const float* __restrict__ usage,
                                             float* __restrict__ emb,
                                             float* __restrict__ e2,
                                             int* __restrict__ counter) {
    int c = blockIdx.x;
    if (c == 0 && threadIdx.x == 0) *counter = 0;
    float u = usage[c];
    u = (u < EPSV) ? EPSV : u;
    float s = 0.f;
#pragma unroll
    for (int i = 0; i < 2; i++) {
        int d = threadIdx.x + i * 256;
        float v = esum[(size_t)c * DS + d] / u;
        emb[(size_t)c * DS + d] = v;
        s += v * v;
    }
#pragma unroll
    for (int o = 32; o; o >>= 1) s += __shfl_down(s, o, 64);
    __shared__ float red[4];
    if ((threadIdx.x & 63) == 0) red[threadIdx.x >> 6] = s;
    __syncthreads();
    if (threadIdx.x == 0) e2[c] = red[0] + red[1] + red[2] + red[3];
}

// ---------------- pack A: x sem -> 256row x 32K bf16 tiles (chunks: 16 hi, 16 lo) ----------------
// tile byte layout (matches LDS image): off = row*64 + ((u ^ ((row>>1)&3))<<4) + (k&7)*2, u = k>>3
__global__ __launch_bounds__(256) void k_packA(const float* __restrict__ x,
                                               char* __restrict__ Ap) {
    __shared__ char ldsH[16384];
    __shared__ char ldsL[16384];
    int mt = blockIdx.x, dc = blockIdx.y;
    int b = mt >> 4;
    int t0 = (mt & 15) * 256;
    int tid = threadIdx.x;
#pragma unroll
    for (int i = 0; i < 8; i++) {
        int idx = tid + i * 256;
        int d = idx >> 6;            // 0..31
        int t4 = idx & 63;           // 0..63
        float4 v = *(const float4*)&x[((size_t)b * DTOT + dc * 32 + d) * TT_DIM + t0 + t4 * 4];
        float va[4] = {v.x, v.y, v.z, v.w};
        int u = d >> 3;
        int kb = (d & 7) * 2;
#pragma unroll
        for (int j = 0; j < 4; j++) {
            int row = t4 * 4 + j;
            unsigned short hi = f2bf(va[j]);
            unsigned short lo = f2bf(va[j] - bf2f(hi));
            int off = row * 64 + ((u ^ ((row >> 1) & 3)) << 4) + kb;
            *(unsigned short*)&ldsH[off] = hi;
            *(unsigned short*)&ldsL[off] = lo;
        }
    }
    __syncthreads();
    char* gH = Ap + ((size_t)mt * 32 + dc) * 16384;
    char* gL = Ap + ((size_t)mt * 32 + 16 + dc) * 16384;
#pragma unroll
    for (int i = 0; i < 4; i++) {
        int off = (tid + i * 256) * 16;
        *(uint4*)&gH[off] = *(const uint4*)&ldsH[off];
        *(uint4*)&gL[off] = *(const uint4*)&ldsL[off];
    }
}

// ---------------- pack B: emb -> 256code x 32K bf16 tiles (chunks: 16 hi, 16 lo) ----------------
__global__ __launch_bounds__(256) void k_packB(const float* __restrict__ emb,
                                               char* __restrict__ Bp) {
    __shared__ char ldsT[16384];
    int nt = blockIdx.x, c = blockIdx.y;
    int lo_flag = (c >= 16);
    int d0 = (lo_flag ? (c - 16) : c) * 32;
    int c0 = nt * 256;
    int tid = threadIdx.x;
#pragma unroll
    for (int i = 0; i < 8; i++) {
        int idx = tid + i * 256;
        int row = idx >> 3;          // code 0..255
        int f4 = idx & 7;            // d-float4 0..7
        float4 v = *(const float4*)&emb[(size_t)(c0 + row) * DS + d0 + f4 * 4];
        float va[4] = {v.x, v.y, v.z, v.w};
        unsigned short wv[4];
#pragma unroll
        for (int j = 0; j < 4; j++) {
            unsigned short hi = f2bf(va[j]);
            wv[j] = lo_flag ? f2bf(va[j] - bf2f(hi)) : hi;
        }
        int u = f4 >> 1;
        int off = row * 64 + ((u ^ ((row >> 1) & 3)) << 4) + (f4 & 1) * 8;
        uint2 pk;
        pk.x = ((unsigned)wv[1] << 16) | wv[0];
        pk.y = ((unsigned)wv[3] << 16) | wv[2];
        *(uint2*)&ldsT[off] = pk;
    }
    __syncthreads();
    char* g = Bp + ((size_t)nt * 32 + c) * 16384;
#pragma unroll
    for (int i = 0; i < 4; i++) {
        int off = (tid + i * 256) * 16;
        *(uint4*)&g[off] = *(const uint4*)&ldsT[off];
    }
}

// ---------------- MFMA distance-argmin: 256x256 tile, 16 waves x 64x64, BK=64 2-slot dbuf ----------------
// Main loop FROZEN from round 14 (869us). Epilogue: round-15 cheap 3-value reduce
// (best, best-idx, sec-VALUE) + post-hoc sec-INDEX via exact-value match (fminf
// propagates values bit-exactly, so v[n]==sec identifies the source candidate).
#define MM(A, B, C) __builtin_amdgcn_mfma_f32_16x16x32_bf16((A), (B), (C), 0, 0, 0)

#define GLDS(SRC, DOFF)                                                              \
    __builtin_amdgcn_global_load_lds(                                                \
        (const __attribute__((address_space(1))) void*)(SRC),                        \
        (__attribute__((address_space(3))) void*)&lds[DOFF], 16, 0, 0)

#define BAR __builtin_amdgcn_s_barrier()
#define VMW0 asm volatile("s_waitcnt vmcnt(0)" ::: "memory")
#define VMNONE (void)0

// stage 64-K step T (chunks 2T, 2T+1) into slot (T&1)
#define STAGE64(T) do {                                                              \
    int sb_ = ((T) & 1) * 65536;                                                     \
    _Pragma("unroll")                                                                \
    for (int h_ = 0; h_ < 2; h_++) {                                                 \
        int c_ = 2 * (T) + h_;                                                       \
        int at_ = (c_ < 32) ? (c_ & 15) : (c_ - 16);                                 \
        int bt_ = (c_ < 32) ? c_ : (c_ - 32);                                        \
        GLDS(Ap_mt + at_ * 16384 + t16, sb_ + h_ * 16384 + t16);                     \
        GLDS(Bp_nt + bt_ * 16384 + t16, sb_ + 32768 + h_ * 16384 + t16);             \
    }                                                                                \
} while (0)

// one 64-K step
#define STEP64(T, DO_STG, VMEND, DO_BAR) do {                                        \
    int sb_ = ((T) & 1) * 65536;                                                     \
    bf16x8 bfv[4], af[4];                                                            \
    _Pragma("unroll")                                                                \
    for (int n_ = 0; n_ < 4; n_++)                                                   \
        bfv[n_] = *(const bf16x8*)&lds[sb_ + 32768 + offB[n_]];                      \
    _Pragma("unroll")                                                                \
    for (int m_ = 0; m_ < 4; m_++)                                                   \
        af[m_] = *(const bf16x8*)&lds[sb_ + offA[m_]];                               \
    if (DO_STG) STAGE64((T) + 1);                                                    \
    __builtin_amdgcn_s_setprio(1);                                                   \
    _Pragma("unroll")                                                                \
    for (int m_ = 0; m_ < 4; m_++)                                                   \
        _Pragma("unroll")                                                            \
        for (int n_ = 0; n_ < 4; n_++)                                               \
            acc[m_][n_] = MM(af[m_], bfv[n_], acc[m_][n_]);                          \
    __builtin_amdgcn_s_setprio(0);                                                   \
    _Pragma("unroll")                                                                \
    for (int n_ = 0; n_ < 4; n_++)                                                   \
        bfv[n_] = *(const bf16x8*)&lds[sb_ + 49152 + offB[n_]];                      \
    _Pragma("unroll")                                                                \
    for (int m_ = 0; m_ < 4; m_++)                                                   \
        af[m_] = *(const bf16x8*)&lds[sb_ + 16384 + offA[m_]];                       \
    __builtin_amdgcn_s_setprio(1);                                                   \
    _Pragma("unroll")                                                                \
    for (int m_ = 0; m_ < 4; m_++)                                                   \
        _Pragma("unroll")                                                            \
        for (int n_ = 0; n_ < 4; n_++)                                               \
            acc[m_][n_] = MM(af[m_], bfv[n_], acc[m_][n_]);                          \
    __builtin_amdgcn_s_setprio(0);                                                   \
    VMEND;                                                                           \
    if (DO_BAR) BAR;                                                                 \
} while (0)

__global__ __launch_bounds__(1024, 4) void k_mfma(const char* __restrict__ Ap,
                                                  const char* __restrict__ Bp,
                                                  const float* __restrict__ e2,
                                                  float* __restrict__ pb,
                                                  int* __restrict__ pi,
                                                  float* __restrict__ ps,
                                                  int* __restrict__ psi) {
    extern __shared__ char lds[];
    // XCD-bijective swizzle: 4096 blocks, 8 XCDs -> 512 consecutive lin per XCD
    int bid = blockIdx.x;
    int lin = (bid >> 3) + (bid & 7) * 512;
    int nt = lin & 15;
    int mt = lin >> 4;

    int tid = threadIdx.x;
    int lane = tid & 63;
    int w = tid >> 6;            // 0..15
    int wr = w >> 2, wc = w & 3; // 4M x 4N waves, each 64x64
    int l15 = lane & 15, lhi = lane >> 4;
    int t16 = tid * 16;          // 1024 threads x 16B = 16 KB

    const char* Ap_mt = Ap + (size_t)mt * 32 * 16384;
    const char* Bp_nt = Bp + (size_t)nt * 32 * 16384;

    int offA[4], offB[4];
#pragma unroll
    for (int m = 0; m < 4; m++) {
        int r = wr * 64 + m * 16 + l15;
        offA[m] = r * 64 + ((lhi ^ ((r >> 1) & 3)) << 4);
    }
#pragma unroll
    for (int n = 0; n < 4; n++) {
        int r = wc * 64 + n * 16 + l15;
        offB[n] = r * 64 + ((lhi ^ ((r >> 1) & 3)) << 4);
    }

    f32x4 acc[4][4];
#pragma unroll
    for (int m = 0; m < 4; m++)
#pragma unroll
        for (int n = 0; n < 4; n++) acc[m][n] = (f32x4){0.f, 0.f, 0.f, 0.f};

    STAGE64(0);
    VMW0;
    BAR;

#pragma unroll 1
    for (int t = 0; t < 23; t++) {
        STEP64(t, 1, VMW0, 1);
    }
    STEP64(23, 0, VMNONE, 0);

    // ---------------- epilogue: 3-value argmin reduce + sec-index by exact match ----------------
    __syncthreads();
    float* rb = (float*)lds;
    float* rs = (float*)(lds + 4096);
    int*   ri = (int*)(lds + 8192);
    int*   rsi = (int*)(lds + 12288);

    float e2v[4];
#pragma unroll
    for (int n = 0; n < 4; n++)
        e2v[n] = e2[nt * 256 + wc * 64 + n * 16 + l15];

#pragma unroll
    for (int m = 0; m < 4; m++) {
#pragma unroll
        for (int r2 = 0; r2 < 4; r2++) {
            float v[4];
#pragma unroll
            for (int n = 0; n < 4; n++)
                v[n] = e2v[n] - 2.f * acc[m][n][r2];
            // round-15 cheap 3-value reduce (best, best-idx, sec value)
            float bst = 3.4e38f, sec = 3.4e38f;
            int bi = 1 << 30;
#pragma unroll
            for (int n = 0; n < 4; n++) {
                int vi = wc * 64 + n * 16 + l15;
                if (v[n] < bst || (v[n] == bst && vi < bi)) { sec = bst; bst = v[n]; bi = vi; }
                else sec = fminf(sec, v[n]);
            }
#pragma unroll
            for (int mask = 1; mask <= 8; mask <<= 1) {
                float ob = __shfl_xor(bst, mask);
                int obi = __shfl_xor(bi, mask);
                float os = __shfl_xor(sec, mask);
                if (ob < bst || (ob == bst && obi < bi)) {
                    sec = fminf(bst, os); bst = ob; bi = obi;
                } else {
                    sec = fminf(sec, ob);
                }
            }
            // sec index: exact-value match over local candidates, min-idx reduce
            int si = 1 << 30;
#pragma unroll
            for (int n = 0; n < 4; n++) {
                int vi = wc * 64 + n * 16 + l15;
                if (v[n] == sec && vi != bi) si = min(si, vi);
            }
#pragma unroll
            for (int mask = 1; mask <= 8; mask <<= 1)
                si = min(si, __shfl_xor(si, mask));
            if (l15 == 0) {
                int rl = wr * 64 + m * 16 + lhi * 4 + r2;
                int slot = wc * 256 + rl;
                rb[slot] = bst; rs[slot] = sec;
                ri[slot] = nt * 256 + bi;
                rsi[slot] = (si < NCODES) ? (nt * 256 + si) : (1 << 30);
            }
        }
    }
    __syncthreads();
    if (tid < 256) {
        float bsv = rb[tid], ssv = rs[tid];
        int biv = ri[tid], siv = rsi[tid];
#pragma unroll
        for (int c = 1; c < 4; c++) {
            float ob = rb[c * 256 + tid];
            float os = rs[c * 256 + tid];
            int oi = ri[c * 256 + tid];
            int osi = rsi[c * 256 + tid];
            if (ob < bsv || (ob == bsv && oi < biv)) {
                if (bsv < os || (bsv == os && biv < osi)) { ssv = bsv; siv = biv; }
                else { ssv = os; siv = osi; }
                bsv = ob; biv = oi;
            } else {
                if (ob < ssv || (ob == ssv && oi < siv)) { ssv = ob; siv = oi; }
            }
        }
        size_t gr = (size_t)mt * 256 + tid;
        pb[(size_t)nt * NROWS + gr] = bsv;
        pi[(size_t)nt * NROWS + gr] = biv;
        ps[(size_t)nt * NROWS + gr] = ssv;
        psi[(size_t)nt * NROWS + gr] = siv;
    }
}

// ---------------- reduce partials -> codes + cand2 + flagged rows ----------------
__global__ __launch_bounds__(256) void k_reduce(const float* __restrict__ pb,
                                                const int* __restrict__ pi,
                                                const float* __restrict__ ps,
                                                const int* __restrict__ psi,
                                                int* __restrict__ codes,
                                                int* __restrict__ cand2,
                                                int* __restrict__ list,
                                                int* __restrict__ counter) {
    int row = blockIdx.x * 256 + threadIdx.x;
    float b = 3.4e38f, s = 3.4e38f;
    int bi = 1 << 30, si = 1 << 30;
    for (int nt = 0; nt < NT; nt++) {
        float b2 = pb[(size_t)nt * NROWS + row];
        int i2 = pi[(size_t)nt * NROWS + row];
        float s2 = ps[(size_t)nt * NROWS + row];
        int si2 = psi[(size_t)nt * NROWS + row];
        if (b2 < b || (b2 == b && i2 < bi)) {
            if (b < s2 || (b == s2 && bi < si2)) { s = b; si = bi; }
            else { s = s2; si = si2; }
            b = b2; bi = i2;
        } else {
            if (b2 < s || (b2 == s && i2 < si)) { s = b2; si = i2; }
        }
    }
    codes[row] = bi;
    cand2[row] = si;
    if (s - b < REFINE_THR) {
        int p = atomicAdd(counter, 1);
        list[p] = row;
    }
}

// ---------------- fp64 2-candidate refine of flagged rows (one wave per row) ----------------
__global__ __launch_bounds__(256) void k_refine(const float* __restrict__ x,
                                                const float* __restrict__ emb,
                                                int* __restrict__ codes,
                                                const int* __restrict__ cand2,
                                                const int* __restrict__ list,
                                                const int* __restrict__ counter) {
    int wid = threadIdx.x >> 6, lane = threadIdx.x & 63;
    int nflag = *counter;
    for (int it = blockIdx.x * 4 + wid; it < nflag; it += gridDim.x * 4) {
        int row = list[it];
        int b = row >> 12;
        int t = row & 4095;
        int c1 = codes[row], c2 = cand2[row];
        if (c2 >= NCODES) continue;
        const float* xb = x + (size_t)b * DTOT * TT_DIM + t;
        double s1 = 0.0, s2 = 0.0;
        for (int d = lane; d < DS; d += 64) {
            double xv = (double)xb[(size_t)d * TT_DIM];
            double d1 = xv - (double)emb[(size_t)c1 * DS + d];
            double d2v = xv - (double)emb[(size_t)c2 * DS + d];
            s1 += d1 * d1;
            s2 += d2v * d2v;
        }
#pragma unroll
        for (int o = 32; o; o >>= 1) {
            s1 += __shfl_down(s1, o, 64);
            s2 += __shfl_down(s2, o, 64);
        }
        if (lane == 0) {
            if (s2 < s1 || (s2 == s1 && c2 < c1)) codes[row] = c2;
        }
    }
}

// ---------------- sem output: vectorized gather (register 4x4 transpose) or float4 copy ----------------
__global__ __launch_bounds__(256) void k_sem(const float* __restrict__ x,
                                             const float* __restrict__ emb,
                                             const int* __restrict__ codes,
                                             const float* __restrict__ sem_probs,
                                             float* __restrict__ out) {
    __shared__ int rowc[TT];
    int b = blockIdx.y, t0 = blockIdx.x * TT;
    bool mask = sem_probs[b] < 0.5f;
    float* outb = out + (size_t)b * DTOT * TT_DIM + t0;
    const float* xb = x + (size_t)b * DTOT * TT_DIM + t0;
    const size_t QOFF = (size_t)BB * DTOT * TT_DIM;

    if (threadIdx.x < TT) {
        int code = codes[b * TT_DIM + t0 + threadIdx.x];
        rowc[threadIdx.x] = code;
        out[QOFF + ((size_t)b * 33) * TT_DIM + t0 + threadIdx.x] = (float)code;
    }
    __syncthreads();

    if (mask) {
#pragma unroll
        for (int i = 0; i < 4; i++) {
            int u = threadIdx.x + i * 256;   // 0..1023
            int d4 = u >> 3;                 // 0..127
            int tg = u & 7;                  // 0..7
            float4 r0 = *(const float4*)&emb[(size_t)rowc[tg * 4 + 0] * DS + d4 * 4];
            float4 r1 = *(const float4*)&emb[(size_t)rowc[tg * 4 + 1] * DS + d4 * 4];
            float4 r2 = *(const float4*)&emb[(size_t)rowc[tg * 4 + 2] * DS + d4 * 4];
            float4 r3 = *(const float4*)&emb[(size_t)rowc[tg * 4 + 3] * DS + d4 * 4];
            float4 c0 = {r0.x, r1.x, r2.x, r3.x};
            float4 c1 = {r0.y, r1.y, r2.y, r3.y};
            float4 c2 = {r0.z, r1.z, r2.z, r3.z};
            float4 c3 = {r0.w, r1.w, r2.w, r3.w};
            *(float4*)&outb[(size_t)(d4 * 4 + 0) * TT_DIM + tg * 4] = c0;
            *(float4*)&outb[(size_t)(d4 * 4 + 1) * TT_DIM + tg * 4] = c1;
            *(float4*)&outb[(size_t)(d4 * 4 + 2) * TT_DIM + tg * 4] = c2;
            *(float4*)&outb[(size_t)(d4 * 4 + 3) * TT_DIM + tg * 4] = c3;
        }
    } else {
#pragma unroll
        for (int i = 0; i < 16; i++) {
            int u = threadIdx.x + i * 256;   // 0..4095
            int d = u >> 3;                  // 0..511
            int tg = u & 7;
            *(float4*)&outb[(size_t)d * TT_DIM + tg * 4] =
                *(const float4*)&xb[(size_t)d * TT_DIM + tg * 4];
        }
    }
}

// ---------------- aco elementwise ----------------
__global__ __launch_bounds__(256) void k_aco(const float* __restrict__ x,
                                             const float* __restrict__ noise,
                                             const float* __restrict__ aco_probs,
                                             float* __restrict__ out) {
    int idx = blockIdx.x * 256 + threadIdx.x;
    int t4 = idx & 1023;
    int bc = idx >> 10;
    int ch = bc & 31;
    int b = bc >> 5;
    const float4 xv = *(const float4*)&x[((size_t)(b * DTOT + DS + ch)) * TT_DIM + t4 * 4];
    const float4 nv = *(const float4*)&noise[((size_t)(b * 32 + ch)) * TT_DIM + t4 * 4];
    float p = aco_probs[b];
    const size_t QOFF = (size_t)BB * DTOT * TT_DIM;

    float zq[4], cq[4];
    float xa[4] = {xv.x, xv.y, xv.z, xv.w};
    float na[4] = {nv.x, nv.y, nv.z, nv.w};
#pragma unroll
    for (int i = 0; i < 4; i++) {
        float zb = tanhf(xa[i]) * HALFV;
        float z;
        if (p < 0.5f) z = rintf(zb);
        else if (p < 0.75f) z = fminf(fmaxf(zb + na[i], -HALFV), HALFV);
        else z = zb;
        zq[i] = z / HALFV;
        cq[i] = fminf(fmaxf(rintf(z + HALFV), 0.f), 15.f);
    }
    float4 qo = {zq[0], zq[1], zq[2], zq[3]};
    float4 co = {cq[0], cq[1], cq[2], cq[3]};
    *(float4*)&out[((size_t)(b * DTOT + DS + ch)) * TT_DIM + t4 * 4] = qo;
    *(float4*)&out[QOFF + ((size_t)(b * 33 + 1 + ch)) * TT_DIM + t4 * 4] = co;
}

extern "C" void kernel_launch(void* const* d_in, const int* in_sizes, int n_in,
                              void* d_out, int out_size, void* d_ws, size_t ws_size,
                              hipStream_t stream) {
    const float* x         = (const float*)d_in[0];
    const float* esum      = (const float*)d_in[1];
    const float* usage     = (const float*)d_in[2];
    const float* sem_probs = (const float*)d_in[3];
    const float* aco_probs = (const float*)d_in[4];
    const float* noise     = (const float*)d_in[5];
    float* out = (float*)d_out;

    char* w = (char*)d_ws;
    float* emb    = (float*)w;                         // 8,388,608
    float* e2     = (float*)(w + 8388608);             // 16,384
    char*  Ap     = w + 8404992;                       // 134,217,728
    char*  Bp     = w + 142622720;                     // 8,388,608
    float* pb     = (float*)(w + 151011328);           // 4,194,304
    int*   pi     = (int*)(w + 155205632);             // 4,194,304
    float* ps     = (float*)(w + 159399936);           // 4,194,304
    int*   psi    = (int*)(w + 163594240);             // 4,194,304
    int*   codes  = (int*)(w + 167788544);             // 262,144
    int*   cand2  = (int*)(w + 168050688);             // 262,144
    int*   list   = (int*)(w + 168312832);             // 262,144
    int*   counter= (int*)(w + 168574976);             // 4

    k_emb<<<NCODES, 256, 0, stream>>>(esum, usage, emb, e2, counter);
    k_packA<<<dim3(MT, 16), 256, 0, stream>>>(x, Ap);
    k_packB<<<dim3(NT, 32), 256, 0, stream>>>(emb, Bp);
    k_mfma<<<NT * MT, 1024, 131072, stream>>>(Ap, Bp, e2, pb, pi, ps, psi);
    k_reduce<<<NROWS / 256, 256, 0, stream>>>(pb, pi, ps, psi, codes, cand2, list, counter);
    k_refine<<<256, 256, 0, stream>>>(x, emb, codes, cand2, list, counter);
    k_sem<<<dim3(TT_DIM / TT, BB), 256, 0, stream>>>(x, emb, codes, sem_probs, out);
    k_aco<<<(BB * 32 * TT_DIM) / (256 * 4), 256, 0, stream>>>(x, noise, aco_probs, out);
}